// Round 7
// baseline (2336.837 us; speedup 1.0000x reference)
//
#include <hip/hip_runtime.h>
#include <cstdio>

#define NODES 153600
#define PJ 150
#define NJETS 1024
#define DEG 16
#define NEDGE (NODES*DEG)
#define HD 256
#define NCL 10

#define LSTR 168   // padded stride (u16) for Ttr rows (336 B)
#define TSTR 76    // padded stride (u16) for Tnat rows (152 B = 38 dw, 38 mod 32 = 6 -> spread)

typedef unsigned short u16;  // fp16 bit pattern
typedef _Float16 f16;
typedef f16 f16x8 __attribute__((ext_vector_type(8)));
typedef u16 u16x8 __attribute__((ext_vector_type(8)));
typedef u16 u16x4 __attribute__((ext_vector_type(4)));
typedef float f32x4 __attribute__((ext_vector_type(4)));

__device__ inline float h2f(u16 u) { union { u16 s; f16 h; } v; v.s = u; return (float)v.h; }
__device__ inline u16 f2h(float f) { union { u16 s; f16 h; } v; v.h = (f16)f; return v.s; }

template<typename T> __device__ inline float ldv(const T* p);
template<> __device__ inline float ldv<float>(const float* p) { return *p; }
template<> __device__ inline float ldv<u16>(const u16* p) { return h2f(*p); }
template<typename T> __device__ inline void stv(T* p, float v);
template<> __device__ inline void stv<float>(float* p, float v) { *p = v; }
template<> __device__ inline void stv<u16>(u16* p, float v) { *p = f2h(v); }

// ---------------- diagnostic ----------------
__global__ void k_diag(float* out, float code) {
  if (blockIdx.x == 0 && threadIdx.x == 0) out[0] = code;
}

// ---------------- graph preprocessing ----------------

__global__ __launch_bounds__(256) void k_dis(const int* __restrict__ tgt, float* __restrict__ dis) {
  int n = blockIdx.x*256 + threadIdx.x;
  if (n >= NODES) return;
  int cnt = 0;
#pragma unroll
  for (int j = 0; j < DEG; ++j) cnt += (tgt[n*DEG + j] != n) ? 1 : 0;
  dis[n] = (cnt > 0) ? rsqrtf((float)cnt) : 0.f;
}

__global__ __launch_bounds__(256) void k_counts(const int* __restrict__ tgt, int* __restrict__ counts) {
  int e = blockIdx.x*256 + threadIdx.x;
  if (e >= NEDGE) return;
  atomicAdd(&counts[tgt[e]], 1);
}

__global__ __launch_bounds__(256) void k_scan(const int* __restrict__ counts, int* __restrict__ rowptr, int* __restrict__ cursor) {
  int j = blockIdx.x*256 + threadIdx.x;
  if (j >= NJETS) return;
  int run = j*PJ*DEG;
  for (int l = 0; l < PJ; ++l) {
    int idx = j*PJ + l;
    int cnt = counts[idx];
    rowptr[idx] = run;
    cursor[idx] = run;
    run += cnt;
  }
  if (j == 0) rowptr[NODES] = NEDGE;
}

__global__ __launch_bounds__(256) void k_fill(const int* __restrict__ src_, const int* __restrict__ tgt_,
                                              const float* __restrict__ dis, int* __restrict__ cursor,
                                              unsigned char* __restrict__ ccol, float* __restrict__ cw) {
  int e = blockIdx.x*256 + threadIdx.x;
  if (e >= NEDGE) return;
  int s = src_[e], t = tgt_[e];
  int pos = atomicAdd(&cursor[t], 1);
  ccol[pos] = (unsigned char)(s % PJ);
  cw[pos] = (s != t) ? -(dis[s]*dis[t]) : 0.f;
}

// ---------------- dense per-jet 2*Laplacian: Lg[jet][160][160] f16 ----------------
__global__ __launch_bounds__(256) void k_prepL(const int* __restrict__ rowptr,
                                               const unsigned char* __restrict__ ccol,
                                               const float* __restrict__ cw,
                                               u16* __restrict__ Lg) {
  int j = blockIdx.x, tid = threadIdx.x;
  u16* L = Lg + (size_t)j*160*160;
  if (tid < 160) {
    u16x8 z = {0,0,0,0,0,0,0,0};
    for (int seg = 0; seg < 20; ++seg) *(u16x8*)&L[tid*160 + seg*8] = z;
    if (tid < PJ) {
      int es = rowptr[j*PJ + tid], ee = rowptr[j*PJ + tid + 1];
      u16* row = L + tid*160;
      for (int e = es; e < ee; ++e) {
        int c = (int)ccol[e];
        row[c] = f2h(h2f(row[c]) + 2.f*cw[e]);   // L2 = 2*Lhat
      }
    }
  }
}

// ---------------- layer 1: fused 5 sparse props (din=3), writes Tall[N][18] fp32 ----------------
__global__ __launch_bounds__(512) void k_cheb3(const float* __restrict__ x,
                                               const int* __restrict__ rowptr,
                                               const unsigned char* __restrict__ ccol,
                                               const float* __restrict__ cw,
                                               float* __restrict__ tall) {
  __shared__ float Ta[450], Tb[450];
  __shared__ float cw_s[PJ*DEG];
  __shared__ u16  col_s[PJ*DEG];
  __shared__ int  rp_s[PJ+1];
  int j = blockIdx.x, tid = threadIdx.x;
  int jb = j*PJ, e0 = jb*DEG;
  for (int i = tid; i < PJ*DEG; i += 512) { cw_s[i] = cw[e0+i]; col_s[i] = (u16)ccol[e0+i]; }
  for (int i = tid; i < PJ+1; i += 512) rp_s[i] = rowptr[jb+i] - e0;
  if (tid < 450) Ta[tid] = x[(size_t)jb*3 + tid];
  __syncthreads();
  int r = tid/3, c = tid - r*3;
  float* cur = Ta; float* oth = Tb;
  if (tid < 450) tall[(size_t)(jb+r)*18 + c] = cur[tid];
  for (int t = 1; t < 6; ++t) {
    if (tid < 450) {
      int es = rp_s[r], ee = rp_s[r+1];
      float acc = 0.f;
      for (int e = es; e < ee; ++e) acc += cw_s[e]*cur[(int)col_s[e]*3 + c];
      float v = (t == 1) ? acc : 2.f*acc - oth[tid];   // oth[tid] = T_{t-2}, own slot
      oth[tid] = v;
      tall[(size_t)(jb+r)*18 + t*3 + c] = v;
    }
    __syncthreads();
    float* tmp = cur; cur = oth; oth = tmp;
  }
}

// out[n,c] = sum_{i<18} Tall[n,i] * W1[i,c]   (W1 flat (6,3,256) == (18,256))
template<typename OT>
__global__ __launch_bounds__(256) void k_gemm1(const float* __restrict__ tall, const float* __restrict__ W1,
                                               OT* __restrict__ outc) {
  __shared__ float wl[18*256];
  __shared__ float tl[64*18];
  int c = threadIdx.x;
  for (int i = c; i < 18*256; i += 256) wl[i] = W1[i];
  int n0 = blockIdx.x*64;
  __syncthreads();
  for (int i = c; i < 64*18; i += 256) tl[i] = tall[(size_t)n0*18 + i];
  __syncthreads();
  for (int n = 0; n < 64; ++n) {
    float acc = 0.f;
#pragma unroll
    for (int i = 0; i < 18; ++i) acc += tl[n*18 + i] * wl[i*256 + c];
    stv(&outc[(size_t)(n0+n)*HD + c], acc);
  }
}

// ---------------- W prep: WT[cout][k] f16, k = term*256 + cin ----------------
__global__ __launch_bounds__(256) void k_prepW(const float* __restrict__ W, u16* __restrict__ WT) {
  int i = blockIdx.x*256 + threadIdx.x;
  if (i >= 256*1536) return;
  int cout = i / 1536, k = i - cout*1536;
  int term = k >> 8, cin = k & 255;
  WT[i] = f2h(W[(size_t)term*65536 + cin*256 + cout]);
}

// ---------------- fused per-jet Chebyshev layer, all-MFMA, 2 blocks/CU ----------------
// LDS: Tnat ping-pong [2][160][76] (48.6K) + Ttr [64][168] (21.5K) = 70.1 KB.
// L A-fragments read from GLOBAL (per-jet 51 KB tile, L2-resident).
template<typename OT>
__global__ __launch_bounds__(512, 4) void k_cheb(const u16* __restrict__ X,
                                                 const u16* __restrict__ WTu,
                                                 const u16* __restrict__ Lg,
                                                 OT* __restrict__ OUTp) {
  __shared__ u16 Tn[2][160*TSTR];
  __shared__ u16 Tt[64*LSTR];
  int j = blockIdx.x, tid = threadIdx.x;
  int jb = j*PJ;
  int lane = tid & 63, wid = tid >> 6;
  int wm = wid >> 2, wn = wid & 3;
  int lr = lane & 15, lg = lane >> 4;
  const f16* WT = (const f16*)WTu;
  const f16* Lj = (const f16*)(Lg + (size_t)j*25600);

  f32x4 acc[5][4];
#pragma unroll
  for (int a = 0; a < 5; ++a)
#pragma unroll
    for (int b = 0; b < 4; ++b) acc[a][b] = (f32x4)0.f;

  for (int q = 0; q < 4; ++q) {
    // stage T0 (natural) from X, zero rows 150..159
    for (int i = tid; i < 160*8; i += 512) {
      int row = i >> 3, seg = i & 7;
      u16x8 v = {0,0,0,0,0,0,0,0};
      if (row < PJ) v = *(const u16x8*)&X[(size_t)(jb+row)*HD + q*64 + seg*8];
      *(u16x8*)&Tn[0][row*TSTR + seg*8] = v;
    }
    __syncthreads();
    // build Ttr[c][r]: lanes sweep c (bank-spread), rows in groups of 8
    for (int i = tid; i < 1280; i += 512) {
      int c = i & 63, m = i >> 6;
      u16x8 v;
#pragma unroll
      for (int u = 0; u < 8; ++u) v[u] = Tn[0][(m*8+u)*TSTR + c];
      *(u16x8*)&Tt[c*LSTR + m*8] = v;
    }
    __syncthreads();
    int cur = 0;
#pragma unroll 1
    for (int t = 0; t < 6; ++t) {
      // ---- weight GEMM: acc += T_t @ W_t (A: LDS natural; B: WT global/L2) ----
      int kbase = t*256 + q*64;
#pragma unroll
      for (int ks = 0; ks < 64; ks += 32) {
        f16x8 a[5], bv[4];
#pragma unroll
        for (int nf = 0; nf < 4; ++nf)
          bv[nf] = *(const f16x8*)&WT[(size_t)(wn*64 + nf*16 + lr)*1536 + kbase + ks + lg*8];
#pragma unroll
        for (int mf = 0; mf < 5; ++mf)
          a[mf] = *(const f16x8*)&Tn[cur][(wm*80 + mf*16 + lr)*TSTR + ks + lg*8];
#pragma unroll
        for (int nf = 0; nf < 4; ++nf)
#pragma unroll
          for (int mf = 0; mf < 5; ++mf)
            acc[mf][nf] = __builtin_amdgcn_mfma_f32_16x16x32_f16(a[mf], bv[nf], acc[mf][nf], 0, 0, 0);
      }
      if (t < 5) {
        // ---- prop MFMA: pacc = L2 @ T_t (A: global L rows; B: Ttr LDS) ----
        f32x4 pacc[5];
#pragma unroll
        for (int mf = 0; mf < 5; ++mf) pacc[mf] = (f32x4)0.f;
#pragma unroll
        for (int ks = 0; ks < 5; ++ks) {
          f16x8 b = *(const f16x8*)&Tt[(wn*16 + lr)*LSTR + ks*32 + lg*8];
#pragma unroll
          for (int mf = 0; mf < 5; ++mf) {
            f16x8 a = *(const f16x8*)&Lj[(wm*80 + mf*16 + lr)*160 + ks*32 + lg*8];
            pacc[mf] = __builtin_amdgcn_mfma_f32_16x16x32_f16(a, b, pacc[mf], 0, 0, 0);
          }
        }
        __syncthreads();   // reads of Tt and Tn[cur^1] complete
        // epilogue: T_{t+1} = pacc - T_{t-1} (0.5*pacc at t=0)
        int oth = cur ^ 1;
        int c = wn*16 + lr;
#pragma unroll
        for (int mf = 0; mf < 5; ++mf) {
          int r0 = wm*80 + mf*16 + lg*4;
          u16x4 o;
#pragma unroll
          for (int e = 0; e < 4; ++e) {
            float v;
            if (t == 0) v = 0.5f*pacc[mf][e];
            else        v = pacc[mf][e] - h2f(Tn[oth][(r0+e)*TSTR + c]);
            o[e] = f2h(v);
            Tn[oth][(r0+e)*TSTR + c] = o[e];
          }
          *(u16x4*)&Tt[c*LSTR + r0] = o;
        }
        __syncthreads();
        cur ^= 1;
      } else {
        __syncthreads();   // fence Tn[cur]/WT reads before next-quarter staging
      }
    }
  }
  // ---- OUT epilogue (HW-verified C/D layout) ----
#pragma unroll
  for (int mf = 0; mf < 5; ++mf) {
    int row = wm*80 + mf*16 + lg*4;
#pragma unroll
    for (int e = 0; e < 4; ++e) {
      int r = row + e;
      if (r < PJ) {
#pragma unroll
        for (int nf = 0; nf < 4; ++nf) {
          int col = wn*64 + nf*16 + lr;
          stv(&OUTp[(size_t)(jb+r)*HD + col], acc[mf][nf][e]);
        }
      }
    }
  }
}

// ---------------- batchnorm (training stats, biased var) + leaky relu ----------------

template<typename OT>
__global__ __launch_bounds__(256) void k_bnstats(const OT* __restrict__ Cc, const float* __restrict__ bias,
                                                 float* __restrict__ stats) {
  int c = threadIdx.x;
  float bc = bias[c];
  float s = 0.f, s2 = 0.f;
  int rows_per = (NODES + gridDim.x - 1) / gridDim.x;
  int r0 = blockIdx.x * rows_per;
  int r1 = min(NODES, r0 + rows_per);
  for (int r = r0; r < r1; ++r) {
    float v = ldv(&Cc[(size_t)r*HD + c]) + bc;
    s += v; s2 += v*v;
  }
  atomicAdd(&stats[c], s);
  atomicAdd(&stats[HD + c], s2);
}

template<typename OT>
__global__ __launch_bounds__(256) void k_bnapply(const OT* __restrict__ Cc, const float* __restrict__ bias,
                                                 const float* __restrict__ stats, const float* __restrict__ g,
                                                 const float* __restrict__ be, u16* __restrict__ hout) {
  const float invN = 1.f/(float)NODES;
  int total = NODES*HD;
  for (int i = blockIdx.x*256 + threadIdx.x; i < total; i += gridDim.x*256) {
    int c = i & (HD-1);
    float m = stats[c]*invN;
    float v = stats[HD+c]*invN - m*m;
    float wq = rsqrtf(v + 1e-5f);
    float val = (ldv(&Cc[i]) + bias[c] - m)*wq*g[c] + be[c];
    hout[i] = f2h((val > 0.f) ? val : 0.01f*val);
  }
}

// ---------------- row L2 normalize (layer 4 output) ----------------

template<typename OT>
__global__ __launch_bounds__(256) void k_rownorm(const OT* __restrict__ Cc, const float* __restrict__ bias,
                                                 u16* __restrict__ hout) {
  int wave = threadIdx.x >> 6, lane = threadIdx.x & 63;
  int n = blockIdx.x*4 + wave;
  float v0 = ldv(&Cc[(size_t)n*HD + lane*4 + 0]) + bias[lane*4 + 0];
  float v1 = ldv(&Cc[(size_t)n*HD + lane*4 + 1]) + bias[lane*4 + 1];
  float v2 = ldv(&Cc[(size_t)n*HD + lane*4 + 2]) + bias[lane*4 + 2];
  float v3 = ldv(&Cc[(size_t)n*HD + lane*4 + 3]) + bias[lane*4 + 3];
  float ss = v0*v0 + v1*v1 + v2*v2 + v3*v3;
  for (int off = 32; off > 0; off >>= 1) ss += __shfl_down(ss, off, 64);
  ss = __shfl(ss, 0, 64);
  float inv = 1.f / fmaxf(sqrtf(ss), 1e-12f);
  hout[(size_t)n*HD + lane*4 + 0] = f2h(v0*inv);
  hout[(size_t)n*HD + lane*4 + 1] = f2h(v1*inv);
  hout[(size_t)n*HD + lane*4 + 2] = f2h(v2*inv);
  hout[(size_t)n*HD + lane*4 + 3] = f2h(v3*inv);
}

// ---------------- distance softmax pooling ----------------

__global__ __launch_bounds__(256) void k_pool(const u16* __restrict__ h, const float* __restrict__ x,
                                              const float* __restrict__ centers, const float* __restrict__ log_temp,
                                              float* __restrict__ out) {
  __shared__ float a_s[PJ][NCL];
  __shared__ float colsum[NCL];
  int j = blockIdx.x;
  int tid = threadIdx.x;
  float T = expf(fminf(fmaxf(log_temp[0], -2.f), 3.f));
  if (tid < PJ) {
    int g = j*PJ + tid;
    float eta = x[(size_t)g*3], phi = x[(size_t)g*3 + 1];
    float d[NCL];
    float dmin = 1e30f;
#pragma unroll
    for (int k = 0; k < NCL; ++k) {
      float dx = eta - centers[2*k], dy = phi - centers[2*k+1];
      d[k] = dx*dx + dy*dy;
      dmin = fminf(dmin, d[k]);
    }
    float s = 0.f, ek[NCL];
#pragma unroll
    for (int k = 0; k < NCL; ++k) { ek[k] = expf(-T*(d[k]-dmin)); s += ek[k]; }
    float invs = 1.f/s;
#pragma unroll
    for (int k = 0; k < NCL; ++k) a_s[tid][k] = ek[k]*invs;
  }
  __syncthreads();
  if (tid < NCL) {
    float s = 0.f;
    for (int n = 0; n < PJ; ++n) s += a_s[n][tid];
    colsum[tid] = s;
  }
  __syncthreads();
  int c = tid;
  float acc[NCL] = {};
  for (int n = 0; n < PJ; ++n) {
    float hv = h2f(h[(size_t)(j*PJ + n)*HD + c]);
#pragma unroll
    for (int k = 0; k < NCL; ++k) acc[k] += a_s[n][k]*hv;
  }
#pragma unroll
  for (int k = 0; k < NCL; ++k)
    out[(size_t)j*(NCL*HD) + k*HD + c] = acc[k] / (colsum[k] + 1e-8f);
}

// ---------------- host ----------------

template<typename OT>
static void run_plan(const float* x, const int* srcA, const int* tgtA,
                     const float* W1, const float* b1, const float* W2, const float* b2,
                     const float* W3, const float* b3, const float* W4, const float* b4,
                     const float* g1, const float* be1, const float* g2, const float* be2,
                     const float* g3, const float* be3, const float* centers, const float* log_temp,
                     float* out, char* wp0, hipStream_t stream) {
  char* wp = wp0;
  auto alloc = [&](size_t b) -> void* {
    void* p = (void*)wp;
    wp += (b + 255) & ~(size_t)255;
    return p;
  };
  u16*   X    = (u16*)alloc((size_t)NODES*HD*2);
  u16*   Y    = (u16*)alloc((size_t)NODES*HD*2);
  OT*    OUT  = (OT*)alloc((size_t)NODES*HD*sizeof(OT));
  float* dis  = (float*)alloc((size_t)NODES*4);
  int*   counts = (int*)alloc((size_t)NODES*4);
  int*   cursor = (int*)alloc((size_t)NODES*4);
  int*   rowptr = (int*)alloc((size_t)(NODES+1)*4);
  unsigned char* ccol = (unsigned char*)alloc((size_t)NEDGE);
  float* cw     = (float*)alloc((size_t)NEDGE*4);
  float* stats  = (float*)alloc((size_t)2*HD*4);
  // aliases into Y: layer-1 Tall (11 MB) first, then Lg (52.4 MB) + Wcat (0.8 MB)
  float* Tall = (float*)Y;
  u16*   Lg   = Y;
  u16*   Wcat = Y + (size_t)NJETS*160*160;

  // graph preprocessing
  hipMemsetAsync(counts, 0, (size_t)NODES*4, stream);
  k_dis<<<(NODES+255)/256, 256, 0, stream>>>(tgtA, dis);
  k_counts<<<(NEDGE+255)/256, 256, 0, stream>>>(tgtA, counts);
  k_scan<<<(NJETS+255)/256, 256, 0, stream>>>(counts, rowptr, cursor);
  k_fill<<<(NEDGE+255)/256, 256, 0, stream>>>(srcA, tgtA, dis, cursor, ccol, cw);

  // ---- layer 1 (din=3): fused props + small GEMM + BN ----
  k_cheb3<<<NJETS, 512, 0, stream>>>(x, rowptr, ccol, cw, Tall);
  k_gemm1<OT><<<NODES/64, 256, 0, stream>>>(Tall, W1, OUT);
  hipMemsetAsync(stats, 0, (size_t)2*HD*4, stream);
  k_bnstats<OT><<<1024, 256, 0, stream>>>(OUT, b1, stats);
  k_bnapply<OT><<<4096, 256, 0, stream>>>(OUT, b1, stats, g1, be1, X);

  // ---- dense Laplacian (after layer 1 frees the Y scratch) ----
  k_prepL<<<NJETS, 256, 0, stream>>>(rowptr, ccol, cw, Lg);

  // ---- layers 2..4: fused all-MFMA Cheb ----
  const float* Ws[3]  = {W2, W3, W4};
  const float* bs[3]  = {b2, b3, b4};
  const float* gs[2]  = {g2, g3};
  const float* bes[2] = {be2, be3};
  for (int L = 0; L < 3; ++L) {
    k_prepW<<<1536, 256, 0, stream>>>(Ws[L], Wcat);
    k_cheb<OT><<<NJETS, 512, 0, stream>>>(X, Wcat, Lg, OUT);
    if (L < 2) {
      hipMemsetAsync(stats, 0, (size_t)2*HD*4, stream);
      k_bnstats<OT><<<1024, 256, 0, stream>>>(OUT, bs[L], stats);
      k_bnapply<OT><<<4096, 256, 0, stream>>>(OUT, bs[L], stats, gs[L], bes[L], X);
    } else {
      k_rownorm<OT><<<NODES/4, 256, 0, stream>>>(OUT, bs[L], X);
    }
  }

  // ---- pooling ----
  k_pool<<<NJETS, 256, 0, stream>>>(X, x, centers, log_temp, out);
}

extern "C" void kernel_launch(void* const* d_in, const int* in_sizes, int n_in,
                              void* d_out, int out_size, void* d_ws, size_t ws_size,
                              hipStream_t stream) {
  (void)in_sizes; (void)n_in; (void)out_size;
  const float* x   = (const float*)d_in[0];
  const int*   ei  = (const int*)d_in[1];
  const int*   srcA = ei;
  const int*   tgtA = ei + NEDGE;
  const float* W1  = (const float*)d_in[3];
  const float* b1  = (const float*)d_in[4];
  const float* W2  = (const float*)d_in[5];
  const float* b2  = (const float*)d_in[6];
  const float* W3  = (const float*)d_in[7];
  const float* b3  = (const float*)d_in[8];
  const float* W4  = (const float*)d_in[9];
  const float* b4  = (const float*)d_in[10];
  const float* g1  = (const float*)d_in[11];
  const float* be1 = (const float*)d_in[12];
  const float* g2  = (const float*)d_in[13];
  const float* be2 = (const float*)d_in[14];
  const float* g3  = (const float*)d_in[15];
  const float* be3 = (const float*)d_in[16];
  const float* centers  = (const float*)d_in[17];
  const float* log_temp = (const float*)d_in[18];
  float* out = (float*)d_out;

  auto rb = [](size_t b) { return (b + 255) & ~(size_t)255; };
  auto plan_bytes = [&](size_t out_esz) {
    return 2*rb((size_t)NODES*HD*2) + rb((size_t)NODES*HD*out_esz)
         + 3*rb((size_t)NODES*4) + rb((size_t)(NODES+1)*4)
         + rb((size_t)NEDGE) + rb((size_t)NEDGE*4) + rb((size_t)2*HD*4);
  };
  size_t needA = plan_bytes(4);
  size_t needB = plan_bytes(2);
  fprintf(stderr, "[kernel_launch] ws_size=%zu needA=%zu needB=%zu\n", ws_size, needA, needB);

  if (d_ws == nullptr || ws_size < needB) {
    float code = 1.0e6f + (float)(ws_size >> 20);
    k_diag<<<1, 1, 0, stream>>>(out, code);
    return;
  }

  if (ws_size >= needA)
    run_plan<float>(x, srcA, tgtA, W1, b1, W2, b2, W3, b3, W4, b4,
                    g1, be1, g2, be2, g3, be3, centers, log_temp,
                    out, (char*)d_ws, stream);
  else
    run_plan<u16>(x, srcA, tgtA, W1, b1, W2, b2, W3, b3, W4, b4,
                  g1, be1, g2, be2, g3, be3, centers, log_temp,
                  out, (char*)d_ws, stream);
}

// Round 8
// 1669.219 us; speedup vs baseline: 1.4000x; 1.4000x over previous
//
#include <hip/hip_runtime.h>
#include <cstdio>

#define NODES 153600
#define PJ 150
#define NJETS 1024
#define DEG 16
#define NEDGE (NODES*DEG)
#define HD 256
#define NCL 10

#define LSTR 168   // padded stride (u16) for Ls/Tt rows: 84 dw ≡ 20 mod 32 -> ~2-way
#define TSTR 76    // padded stride (u16) for Tn rows: 38 dw ≡ 6 mod 32 -> spread

typedef unsigned short u16;  // fp16 bit pattern
typedef _Float16 f16;
typedef f16 f16x8 __attribute__((ext_vector_type(8)));
typedef u16 u16x8 __attribute__((ext_vector_type(8)));
typedef u16 u16x4 __attribute__((ext_vector_type(4)));
typedef float f32x4 __attribute__((ext_vector_type(4)));

__device__ inline float h2f(u16 u) { union { u16 s; f16 h; } v; v.s = u; return (float)v.h; }
__device__ inline u16 f2h(float f) { union { u16 s; f16 h; } v; v.h = (f16)f; return v.s; }

template<typename T> __device__ inline float ldv(const T* p);
template<> __device__ inline float ldv<float>(const float* p) { return *p; }
template<> __device__ inline float ldv<u16>(const u16* p) { return h2f(*p); }
template<typename T> __device__ inline void stv(T* p, float v);
template<> __device__ inline void stv<float>(float* p, float v) { *p = v; }
template<> __device__ inline void stv<u16>(u16* p, float v) { *p = f2h(v); }

// ---------------- diagnostic ----------------
__global__ void k_diag(float* out, float code) {
  if (blockIdx.x == 0 && threadIdx.x == 0) out[0] = code;
}

// ---------------- graph preprocessing ----------------

__global__ __launch_bounds__(256) void k_dis(const int* __restrict__ tgt, float* __restrict__ dis) {
  int n = blockIdx.x*256 + threadIdx.x;
  if (n >= NODES) return;
  int cnt = 0;
#pragma unroll
  for (int j = 0; j < DEG; ++j) cnt += (tgt[n*DEG + j] != n) ? 1 : 0;
  dis[n] = (cnt > 0) ? rsqrtf((float)cnt) : 0.f;
}

__global__ __launch_bounds__(256) void k_counts(const int* __restrict__ tgt, int* __restrict__ counts) {
  int e = blockIdx.x*256 + threadIdx.x;
  if (e >= NEDGE) return;
  atomicAdd(&counts[tgt[e]], 1);
}

__global__ __launch_bounds__(256) void k_scan(const int* __restrict__ counts, int* __restrict__ rowptr, int* __restrict__ cursor) {
  int j = blockIdx.x*256 + threadIdx.x;
  if (j >= NJETS) return;
  int run = j*PJ*DEG;
  for (int l = 0; l < PJ; ++l) {
    int idx = j*PJ + l;
    int cnt = counts[idx];
    rowptr[idx] = run;
    cursor[idx] = run;
    run += cnt;
  }
  if (j == 0) rowptr[NODES] = NEDGE;
}

__global__ __launch_bounds__(256) void k_fill(const int* __restrict__ src_, const int* __restrict__ tgt_,
                                              const float* __restrict__ dis, int* __restrict__ cursor,
                                              unsigned char* __restrict__ ccol, float* __restrict__ cw) {
  int e = blockIdx.x*256 + threadIdx.x;
  if (e >= NEDGE) return;
  int s = src_[e], t = tgt_[e];
  int pos = atomicAdd(&cursor[t], 1);
  ccol[pos] = (unsigned char)(s % PJ);
  cw[pos] = (s != t) ? -(dis[s]*dis[t]) : 0.f;
}

// ---------------- dense per-jet 2*Laplacian: Lg[jet][160][160] f16 ----------------
__global__ __launch_bounds__(256) void k_prepL(const int* __restrict__ rowptr,
                                               const unsigned char* __restrict__ ccol,
                                               const float* __restrict__ cw,
                                               u16* __restrict__ Lg) {
  int j = blockIdx.x, tid = threadIdx.x;
  u16* L = Lg + (size_t)j*160*160;
  if (tid < 160) {
    u16x8 z = {0,0,0,0,0,0,0,0};
    for (int seg = 0; seg < 20; ++seg) *(u16x8*)&L[tid*160 + seg*8] = z;
    if (tid < PJ) {
      int es = rowptr[j*PJ + tid], ee = rowptr[j*PJ + tid + 1];
      u16* row = L + tid*160;
      for (int e = es; e < ee; ++e) {
        int c = (int)ccol[e];
        row[c] = f2h(h2f(row[c]) + 2.f*cw[e]);   // L2 = 2*Lhat
      }
    }
  }
}

// ---------------- layer 1: fused 5 sparse props (din=3), writes Tall[N][18] fp32 ----------------
__global__ __launch_bounds__(512) void k_cheb3(const float* __restrict__ x,
                                               const int* __restrict__ rowptr,
                                               const unsigned char* __restrict__ ccol,
                                               const float* __restrict__ cw,
                                               float* __restrict__ tall) {
  __shared__ float Ta[450], Tb[450];
  __shared__ float cw_s[PJ*DEG];
  __shared__ u16  col_s[PJ*DEG];
  __shared__ int  rp_s[PJ+1];
  int j = blockIdx.x, tid = threadIdx.x;
  int jb = j*PJ, e0 = jb*DEG;
  for (int i = tid; i < PJ*DEG; i += 512) { cw_s[i] = cw[e0+i]; col_s[i] = (u16)ccol[e0+i]; }
  for (int i = tid; i < PJ+1; i += 512) rp_s[i] = rowptr[jb+i] - e0;
  if (tid < 450) Ta[tid] = x[(size_t)jb*3 + tid];
  __syncthreads();
  int r = tid/3, c = tid - r*3;
  float* cur = Ta; float* oth = Tb;
  if (tid < 450) tall[(size_t)(jb+r)*18 + c] = cur[tid];
  for (int t = 1; t < 6; ++t) {
    if (tid < 450) {
      int es = rp_s[r], ee = rp_s[r+1];
      float acc = 0.f;
      for (int e = es; e < ee; ++e) acc += cw_s[e]*cur[(int)col_s[e]*3 + c];
      float v = (t == 1) ? acc : 2.f*acc - oth[tid];
      oth[tid] = v;
      tall[(size_t)(jb+r)*18 + t*3 + c] = v;
    }
    __syncthreads();
    float* tmp = cur; cur = oth; oth = tmp;
  }
}

// out[n,c] = sum_{i<18} Tall[n,i] * W1[i,c]
template<typename OT>
__global__ __launch_bounds__(256) void k_gemm1(const float* __restrict__ tall, const float* __restrict__ W1,
                                               OT* __restrict__ outc) {
  __shared__ float wl[18*256];
  __shared__ float tl[64*18];
  int c = threadIdx.x;
  for (int i = c; i < 18*256; i += 256) wl[i] = W1[i];
  int n0 = blockIdx.x*64;
  __syncthreads();
  for (int i = c; i < 64*18; i += 256) tl[i] = tall[(size_t)n0*18 + i];
  __syncthreads();
  for (int n = 0; n < 64; ++n) {
    float acc = 0.f;
#pragma unroll
    for (int i = 0; i < 18; ++i) acc += tl[n*18 + i] * wl[i*256 + c];
    stv(&outc[(size_t)(n0+n)*HD + c], acc);
  }
}

// ---------------- W prep: WT[cout][k] f16, k = term*256 + cin ----------------
__global__ __launch_bounds__(256) void k_prepW(const float* __restrict__ W, u16* __restrict__ WT) {
  int i = blockIdx.x*256 + threadIdx.x;
  if (i >= 256*1536) return;
  int cout = i / 1536, k = i - cout*1536;
  int term = k >> 8, cin = k & 255;
  WT[i] = f2h(W[(size_t)term*65536 + cin*256 + cout]);
}

// ---------------- fused per-jet Chebyshev layer, all-MFMA, quarter-paired ----------------
// Block = jet (512 thr, 8 waves 2Mx4N). LDS: L [160][168] 53.8K + Tn[2][160][76] 48.6K
// + Tt[2][64][168] 43K = 145.4 KB (1 block/CU). Two independent quarter chains share
// each barrier; T_{t-1} lives in registers (owner-exclusive u16x4). BN stats fused
// into the epilogue (shfl-reduce + lg==0 atomics).
template<typename OT>
__global__ __launch_bounds__(512, 2) void k_cheb(const u16* __restrict__ X,
                                                 const u16* __restrict__ WTu,
                                                 const u16* __restrict__ Lg,
                                                 const float* __restrict__ bias,
                                                 float* __restrict__ stats,
                                                 OT* __restrict__ OUTp) {
  __shared__ u16 Ls[160*LSTR];
  __shared__ u16 Tn[2][160*TSTR];
  __shared__ u16 Tt[2][64*LSTR];
  int j = blockIdx.x, tid = threadIdx.x;
  int jb = j*PJ;
  int lane = tid & 63, wid = tid >> 6;
  int wm = wid >> 2, wn = wid & 3;
  int lr = lane & 15, lg = lane >> 4;
  int cown = wn*16 + lr;
  const f16* WT = (const f16*)WTu;

  // stage dense L once
  {
    const u16* src = Lg + (size_t)j*25600;
    for (int i = tid; i < 3200; i += 512) {
      int row = i/20, seg = i - row*20;
      *(u16x8*)&Ls[row*LSTR + seg*8] = *(const u16x8*)&src[row*160 + seg*8];
    }
  }
  f32x4 acc[5][4];
#pragma unroll
  for (int a = 0; a < 5; ++a)
#pragma unroll
    for (int b = 0; b < 4; ++b) acc[a][b] = (f32x4)0.f;

  for (int qp = 0; qp < 2; ++qp) {
    __syncthreads();   // prior-pair reads done (and L staged at qp=0)
    // stage Tn[0], Tn[1] from X quarters (qp*2, qp*2+1); zero rows 150..159
    for (int i = tid; i < 2560; i += 512) {
      int h = (i >= 1280) ? 1 : 0;
      int rem = i - h*1280;
      int row = rem >> 3, seg = rem & 7;
      u16x8 v = {0,0,0,0,0,0,0,0};
      if (row < PJ) v = *(const u16x8*)&X[(size_t)(jb+row)*HD + (qp*2+h)*64 + seg*8];
      *(u16x8*)&Tn[h][row*TSTR + seg*8] = v;
    }
    __syncthreads();
    // build Ttr (bank-spread mapping) + own-slot T0 regs
    for (int i = tid; i < 2560; i += 512) {
      int h = (i >= 1280) ? 1 : 0;
      int rem = i - h*1280;
      int c = rem & 63, m = rem >> 6;
      u16x8 v;
#pragma unroll
      for (int u = 0; u < 8; ++u) v[u] = Tn[h][(m*8+u)*TSTR + c];
      *(u16x8*)&Tt[h][c*LSTR + m*8] = v;
    }
    u16x4 tcur[2][5], tprev[2][5];
#pragma unroll
    for (int h = 0; h < 2; ++h)
#pragma unroll
      for (int mf = 0; mf < 5; ++mf) {
        int r0 = wm*80 + mf*16 + lg*4;
#pragma unroll
        for (int e = 0; e < 4; ++e) tcur[h][mf][e] = Tn[h][(r0+e)*TSTR + cown];
        tprev[h][mf] = tcur[h][mf];
      }
    __syncthreads();
#pragma unroll 1
    for (int t = 0; t < 6; ++t) {
      // ---- weight GEMM, both halves: acc += T_t @ W_t ----
#pragma unroll
      for (int h = 0; h < 2; ++h) {
        int kbase = t*256 + (qp*2+h)*64;
#pragma unroll
        for (int ks = 0; ks < 64; ks += 32) {
          f16x8 a[5], bv[4];
#pragma unroll
          for (int nf = 0; nf < 4; ++nf)
            bv[nf] = *(const f16x8*)&WT[(size_t)(wn*64 + nf*16 + lr)*1536 + kbase + ks + lg*8];
#pragma unroll
          for (int mf = 0; mf < 5; ++mf)
            a[mf] = *(const f16x8*)&Tn[h][(wm*80 + mf*16 + lr)*TSTR + ks + lg*8];
#pragma unroll
          for (int nf = 0; nf < 4; ++nf)
#pragma unroll
            for (int mf = 0; mf < 5; ++mf)
              acc[mf][nf] = __builtin_amdgcn_mfma_f32_16x16x32_f16(a[mf], bv[nf], acc[mf][nf], 0, 0, 0);
        }
      }
      if (t < 5) {
        // ---- prop MFMA, both halves (shared Ls A-frags): pacc = L2 @ T_t ----
        f32x4 pacc[2][5];
#pragma unroll
        for (int h = 0; h < 2; ++h)
#pragma unroll
          for (int mf = 0; mf < 5; ++mf) pacc[h][mf] = (f32x4)0.f;
#pragma unroll
        for (int ks = 0; ks < 5; ++ks) {
          f16x8 b0 = *(const f16x8*)&Tt[0][(wn*16 + lr)*LSTR + ks*32 + lg*8];
          f16x8 b1 = *(const f16x8*)&Tt[1][(wn*16 + lr)*LSTR + ks*32 + lg*8];
#pragma unroll
          for (int mf = 0; mf < 5; ++mf) {
            f16x8 a = *(const f16x8*)&Ls[(wm*80 + mf*16 + lr)*LSTR + ks*32 + lg*8];
            pacc[0][mf] = __builtin_amdgcn_mfma_f32_16x16x32_f16(a, b0, pacc[0][mf], 0, 0, 0);
            pacc[1][mf] = __builtin_amdgcn_mfma_f32_16x16x32_f16(a, b1, pacc[1][mf], 0, 0, 0);
          }
        }
        __syncthreads();   // all Tn/Tt reads of term t complete
        // epilogue: T_{t+1} = pacc - T_{t-1} (0.5*pacc at t=0); owner-exclusive slots
#pragma unroll
        for (int h = 0; h < 2; ++h)
#pragma unroll
          for (int mf = 0; mf < 5; ++mf) {
            int r0 = wm*80 + mf*16 + lg*4;
            u16x4 o;
#pragma unroll
            for (int e = 0; e < 4; ++e) {
              float v = (t == 0) ? 0.5f*pacc[h][mf][e]
                                 : pacc[h][mf][e] - h2f(tprev[h][mf][e]);
              o[e] = f2h(v);
              Tn[h][(r0+e)*TSTR + cown] = o[e];
            }
            *(u16x4*)&Tt[h][cown*LSTR + r0] = o;
            tprev[h][mf] = tcur[h][mf];
            tcur[h][mf] = o;
          }
        __syncthreads();
      }
    }
  }
  // ---- OUT epilogue + fused BN stats ----
#pragma unroll
  for (int nf = 0; nf < 4; ++nf) {
    int col = wn*64 + nf*16 + lr;
    float bc = bias[col];
    float s = 0.f, s2 = 0.f;
#pragma unroll
    for (int mf = 0; mf < 5; ++mf) {
      int row = wm*80 + mf*16 + lg*4;
#pragma unroll
      for (int e = 0; e < 4; ++e) {
        int r = row + e;
        if (r < PJ) {
          float v = acc[mf][nf][e];
          stv(&OUTp[(size_t)(jb+r)*HD + col], v);
          float vb = v + bc;
          s += vb; s2 += vb*vb;
        }
      }
    }
    // lanes lg=0..3 share col: reduce over lg (lane = lg*16+lr) then one atomic
    s  += __shfl_xor(s, 16, 64);  s  += __shfl_xor(s, 32, 64);
    s2 += __shfl_xor(s2, 16, 64); s2 += __shfl_xor(s2, 32, 64);
    if (lg == 0) {
      atomicAdd(&stats[col], s);
      atomicAdd(&stats[HD + col], s2);
    }
  }
}

// ---------------- batchnorm stats (layer 1 only) ----------------

template<typename OT>
__global__ __launch_bounds__(256) void k_bnstats(const OT* __restrict__ Cc, const float* __restrict__ bias,
                                                 float* __restrict__ stats) {
  int c = threadIdx.x;
  float bc = bias[c];
  float s = 0.f, s2 = 0.f;
  int rows_per = (NODES + gridDim.x - 1) / gridDim.x;
  int r0 = blockIdx.x * rows_per;
  int r1 = min(NODES, r0 + rows_per);
  for (int r = r0; r < r1; ++r) {
    float v = ldv(&Cc[(size_t)r*HD + c]) + bc;
    s += v; s2 += v*v;
  }
  atomicAdd(&stats[c], s);
  atomicAdd(&stats[HD + c], s2);
}

template<typename OT>
__global__ __launch_bounds__(256) void k_bnapply(const OT* __restrict__ Cc, const float* __restrict__ bias,
                                                 const float* __restrict__ stats, const float* __restrict__ g,
                                                 const float* __restrict__ be, u16* __restrict__ hout) {
  const float invN = 1.f/(float)NODES;
  int total = NODES*HD;
  for (int i = blockIdx.x*256 + threadIdx.x; i < total; i += gridDim.x*256) {
    int c = i & (HD-1);
    float m = stats[c]*invN;
    float v = stats[HD+c]*invN - m*m;
    float wq = rsqrtf(v + 1e-5f);
    float val = (ldv(&Cc[i]) + bias[c] - m)*wq*g[c] + be[c];
    hout[i] = f2h((val > 0.f) ? val : 0.01f*val);
  }
}

// ---------------- row L2 normalize (layer 4 output) ----------------

template<typename OT>
__global__ __launch_bounds__(256) void k_rownorm(const OT* __restrict__ Cc, const float* __restrict__ bias,
                                                 u16* __restrict__ hout) {
  int wave = threadIdx.x >> 6, lane = threadIdx.x & 63;
  int n = blockIdx.x*4 + wave;
  float v0 = ldv(&Cc[(size_t)n*HD + lane*4 + 0]) + bias[lane*4 + 0];
  float v1 = ldv(&Cc[(size_t)n*HD + lane*4 + 1]) + bias[lane*4 + 1];
  float v2 = ldv(&Cc[(size_t)n*HD + lane*4 + 2]) + bias[lane*4 + 2];
  float v3 = ldv(&Cc[(size_t)n*HD + lane*4 + 3]) + bias[lane*4 + 3];
  float ss = v0*v0 + v1*v1 + v2*v2 + v3*v3;
  for (int off = 32; off > 0; off >>= 1) ss += __shfl_down(ss, off, 64);
  ss = __shfl(ss, 0, 64);
  float inv = 1.f / fmaxf(sqrtf(ss), 1e-12f);
  hout[(size_t)n*HD + lane*4 + 0] = f2h(v0*inv);
  hout[(size_t)n*HD + lane*4 + 1] = f2h(v1*inv);
  hout[(size_t)n*HD + lane*4 + 2] = f2h(v2*inv);
  hout[(size_t)n*HD + lane*4 + 3] = f2h(v3*inv);
}

// ---------------- distance softmax pooling ----------------

__global__ __launch_bounds__(256) void k_pool(const u16* __restrict__ h, const float* __restrict__ x,
                                              const float* __restrict__ centers, const float* __restrict__ log_temp,
                                              float* __restrict__ out) {
  __shared__ float a_s[PJ][NCL];
  __shared__ float colsum[NCL];
  int j = blockIdx.x;
  int tid = threadIdx.x;
  float T = expf(fminf(fmaxf(log_temp[0], -2.f), 3.f));
  if (tid < PJ) {
    int g = j*PJ + tid;
    float eta = x[(size_t)g*3], phi = x[(size_t)g*3 + 1];
    float d[NCL];
    float dmin = 1e30f;
#pragma unroll
    for (int k = 0; k < NCL; ++k) {
      float dx = eta - centers[2*k], dy = phi - centers[2*k+1];
      d[k] = dx*dx + dy*dy;
      dmin = fminf(dmin, d[k]);
    }
    float s = 0.f, ek[NCL];
#pragma unroll
    for (int k = 0; k < NCL; ++k) { ek[k] = expf(-T*(d[k]-dmin)); s += ek[k]; }
    float invs = 1.f/s;
#pragma unroll
    for (int k = 0; k < NCL; ++k) a_s[tid][k] = ek[k]*invs;
  }
  __syncthreads();
  if (tid < NCL) {
    float s = 0.f;
    for (int n = 0; n < PJ; ++n) s += a_s[n][tid];
    colsum[tid] = s;
  }
  __syncthreads();
  int c = tid;
  float acc[NCL] = {};
  for (int n = 0; n < PJ; ++n) {
    float hv = h2f(h[(size_t)(j*PJ + n)*HD + c]);
#pragma unroll
    for (int k = 0; k < NCL; ++k) acc[k] += a_s[n][k]*hv;
  }
#pragma unroll
  for (int k = 0; k < NCL; ++k)
    out[(size_t)j*(NCL*HD) + k*HD + c] = acc[k] / (colsum[k] + 1e-8f);
}

// ---------------- host ----------------

template<typename OT>
static void run_plan(const float* x, const int* srcA, const int* tgtA,
                     const float* W1, const float* b1, const float* W2, const float* b2,
                     const float* W3, const float* b3, const float* W4, const float* b4,
                     const float* g1, const float* be1, const float* g2, const float* be2,
                     const float* g3, const float* be3, const float* centers, const float* log_temp,
                     float* out, char* wp0, hipStream_t stream) {
  char* wp = wp0;
  auto alloc = [&](size_t b) -> void* {
    void* p = (void*)wp;
    wp += (b + 255) & ~(size_t)255;
    return p;
  };
  u16*   X    = (u16*)alloc((size_t)NODES*HD*2);
  u16*   Y    = (u16*)alloc((size_t)NODES*HD*2);
  OT*    OUT  = (OT*)alloc((size_t)NODES*HD*sizeof(OT));
  float* dis  = (float*)alloc((size_t)NODES*4);
  int*   counts = (int*)alloc((size_t)NODES*4);
  int*   cursor = (int*)alloc((size_t)NODES*4);
  int*   rowptr = (int*)alloc((size_t)(NODES+1)*4);
  unsigned char* ccol = (unsigned char*)alloc((size_t)NEDGE);
  float* cw     = (float*)alloc((size_t)NEDGE*4);
  float* stats  = (float*)alloc((size_t)2*HD*4);
  // aliases into Y: layer-1 Tall (11 MB) first, then Lg (52.4 MB) + Wcat (0.8 MB)
  float* Tall = (float*)Y;
  u16*   Lg   = Y;
  u16*   Wcat = Y + (size_t)NJETS*160*160;

  // graph preprocessing
  hipMemsetAsync(counts, 0, (size_t)NODES*4, stream);
  k_dis<<<(NODES+255)/256, 256, 0, stream>>>(tgtA, dis);
  k_counts<<<(NEDGE+255)/256, 256, 0, stream>>>(tgtA, counts);
  k_scan<<<(NJETS+255)/256, 256, 0, stream>>>(counts, rowptr, cursor);
  k_fill<<<(NEDGE+255)/256, 256, 0, stream>>>(srcA, tgtA, dis, cursor, ccol, cw);

  // ---- layer 1 (din=3): fused props + small GEMM + BN ----
  k_cheb3<<<NJETS, 512, 0, stream>>>(x, rowptr, ccol, cw, Tall);
  k_gemm1<OT><<<NODES/64, 256, 0, stream>>>(Tall, W1, OUT);
  hipMemsetAsync(stats, 0, (size_t)2*HD*4, stream);
  k_bnstats<OT><<<1024, 256, 0, stream>>>(OUT, b1, stats);
  k_bnapply<OT><<<4096, 256, 0, stream>>>(OUT, b1, stats, g1, be1, X);

  // ---- dense Laplacian (after layer 1 frees the Y scratch) ----
  k_prepL<<<NJETS, 256, 0, stream>>>(rowptr, ccol, cw, Lg);

  // ---- layers 2..4: fused all-MFMA Cheb (stats fused into epilogue) ----
  const float* Ws[3]  = {W2, W3, W4};
  const float* bs[3]  = {b2, b3, b4};
  const float* gs[2]  = {g2, g3};
  const float* bes[2] = {be2, be3};
  for (int L = 0; L < 3; ++L) {
    k_prepW<<<1536, 256, 0, stream>>>(Ws[L], Wcat);
    hipMemsetAsync(stats, 0, (size_t)2*HD*4, stream);
    k_cheb<OT><<<NJETS, 512, 0, stream>>>(X, Wcat, Lg, bs[L], stats, OUT);
    if (L < 2) {
      k_bnapply<OT><<<4096, 256, 0, stream>>>(OUT, bs[L], stats, gs[L], bes[L], X);
    } else {
      k_rownorm<OT><<<NODES/4, 256, 0, stream>>>(OUT, bs[L], X);
    }
  }

  // ---- pooling ----
  k_pool<<<NJETS, 256, 0, stream>>>(X, x, centers, log_temp, out);
}

extern "C" void kernel_launch(void* const* d_in, const int* in_sizes, int n_in,
                              void* d_out, int out_size, void* d_ws, size_t ws_size,
                              hipStream_t stream) {
  (void)in_sizes; (void)n_in; (void)out_size;
  const float* x   = (const float*)d_in[0];
  const int*   ei  = (const int*)d_in[1];
  const int*   srcA = ei;
  const int*   tgtA = ei + NEDGE;
  const float* W1  = (const float*)d_in[3];
  const float* b1  = (const float*)d_in[4];
  const float* W2  = (const float*)d_in[5];
  const float* b2  = (const float*)d_in[6];
  const float* W3  = (const float*)d_in[7];
  const float* b3  = (const float*)d_in[8];
  const float* W4  = (const float*)d_in[9];
  const float* b4  = (const float*)d_in[10];
  const float* g1  = (const float*)d_in[11];
  const float* be1 = (const float*)d_in[12];
  const float* g2  = (const float*)d_in[13];
  const float* be2 = (const float*)d_in[14];
  const float* g3  = (const float*)d_in[15];
  const float* be3 = (const float*)d_in[16];
  const float* centers  = (const float*)d_in[17];
  const float* log_temp = (const float*)d_in[18];
  float* out = (float*)d_out;

  auto rb = [](size_t b) { return (b + 255) & ~(size_t)255; };
  auto plan_bytes = [&](size_t out_esz) {
    return 2*rb((size_t)NODES*HD*2) + rb((size_t)NODES*HD*out_esz)
         + 3*rb((size_t)NODES*4) + rb((size_t)(NODES+1)*4)
         + rb((size_t)NEDGE) + rb((size_t)NEDGE*4) + rb((size_t)2*HD*4);
  };
  size_t needA = plan_bytes(4);
  size_t needB = plan_bytes(2);
  fprintf(stderr, "[kernel_launch] ws_size=%zu needA=%zu needB=%zu\n", ws_size, needA, needB);

  if (d_ws == nullptr || ws_size < needB) {
    float code = 1.0e6f + (float)(ws_size >> 20);
    k_diag<<<1, 1, 0, stream>>>(out, code);
    return;
  }

  if (ws_size >= needA)
    run_plan<float>(x, srcA, tgtA, W1, b1, W2, b2, W3, b3, W4, b4,
                    g1, be1, g2, be2, g3, be3, centers, log_temp,
                    out, (char*)d_ws, stream);
  else
    run_plan<u16>(x, srcA, tgtA, W1, b1, W2, b2, W3, b3, W4, b4,
                  g1, be1, g2, be2, g3, be3, centers, log_temp,
                  out, (char*)d_ws, stream);
}

// Round 9
// 1543.716 us; speedup vs baseline: 1.5138x; 1.0813x over previous
//
#include <hip/hip_runtime.h>
#include <cstdio>

#define NODES 153600
#define PJ 150
#define NJETS 1024
#define DEG 16
#define NEDGE (NODES*DEG)
#define HD 256
#define NCL 10

#define LSTR 168   // padded stride (u16) for Ls/Tt rows: 84 dw ≡ 20 mod 32 -> ~2-way
#define TSTR 76    // padded stride (u16) for Tn rows: 38 dw ≡ 6 mod 32 -> spread

typedef unsigned short u16;  // fp16 bit pattern
typedef _Float16 f16;
typedef f16 f16x8 __attribute__((ext_vector_type(8)));
typedef u16 u16x8 __attribute__((ext_vector_type(8)));
typedef u16 u16x4 __attribute__((ext_vector_type(4)));
typedef float f32x4 __attribute__((ext_vector_type(4)));

__device__ inline float h2f(u16 u) { union { u16 s; f16 h; } v; v.s = u; return (float)v.h; }
__device__ inline u16 f2h(float f) { union { u16 s; f16 h; } v; v.h = (f16)f; return v.s; }

template<typename T> __device__ inline float ldv(const T* p);
template<> __device__ inline float ldv<float>(const float* p) { return *p; }
template<> __device__ inline float ldv<u16>(const u16* p) { return h2f(*p); }
template<typename T> __device__ inline void stv(T* p, float v);
template<> __device__ inline void stv<float>(float* p, float v) { *p = v; }
template<> __device__ inline void stv<u16>(u16* p, float v) { *p = f2h(v); }

// ---------------- diagnostic ----------------
__global__ void k_diag(float* out, float code) {
  if (blockIdx.x == 0 && threadIdx.x == 0) out[0] = code;
}

// ---------------- graph preprocessing ----------------

__global__ __launch_bounds__(256) void k_dis(const int* __restrict__ tgt, float* __restrict__ dis) {
  int n = blockIdx.x*256 + threadIdx.x;
  if (n >= NODES) return;
  int cnt = 0;
#pragma unroll
  for (int j = 0; j < DEG; ++j) cnt += (tgt[n*DEG + j] != n) ? 1 : 0;
  dis[n] = (cnt > 0) ? rsqrtf((float)cnt) : 0.f;
}

__global__ __launch_bounds__(256) void k_counts(const int* __restrict__ tgt, int* __restrict__ counts) {
  int e = blockIdx.x*256 + threadIdx.x;
  if (e >= NEDGE) return;
  atomicAdd(&counts[tgt[e]], 1);
}

__global__ __launch_bounds__(256) void k_scan(const int* __restrict__ counts, int* __restrict__ rowptr, int* __restrict__ cursor) {
  int j = blockIdx.x*256 + threadIdx.x;
  if (j >= NJETS) return;
  int run = j*PJ*DEG;
  for (int l = 0; l < PJ; ++l) {
    int idx = j*PJ + l;
    int cnt = counts[idx];
    rowptr[idx] = run;
    cursor[idx] = run;
    run += cnt;
  }
  if (j == 0) rowptr[NODES] = NEDGE;
}

__global__ __launch_bounds__(256) void k_fill(const int* __restrict__ src_, const int* __restrict__ tgt_,
                                              const float* __restrict__ dis, int* __restrict__ cursor,
                                              unsigned char* __restrict__ ccol, float* __restrict__ cw) {
  int e = blockIdx.x*256 + threadIdx.x;
  if (e >= NEDGE) return;
  int s = src_[e], t = tgt_[e];
  int pos = atomicAdd(&cursor[t], 1);
  ccol[pos] = (unsigned char)(s % PJ);
  cw[pos] = (s != t) ? -(dis[s]*dis[t]) : 0.f;
}

// ---------------- dense per-jet 2*Laplacian: Lg[jet][160][160] f16 ----------------
__global__ __launch_bounds__(256) void k_prepL(const int* __restrict__ rowptr,
                                               const unsigned char* __restrict__ ccol,
                                               const float* __restrict__ cw,
                                               u16* __restrict__ Lg) {
  int j = blockIdx.x, tid = threadIdx.x;
  u16* L = Lg + (size_t)j*160*160;
  if (tid < 160) {
    u16x8 z = {0,0,0,0,0,0,0,0};
    for (int seg = 0; seg < 20; ++seg) *(u16x8*)&L[tid*160 + seg*8] = z;
    if (tid < PJ) {
      int es = rowptr[j*PJ + tid], ee = rowptr[j*PJ + tid + 1];
      u16* row = L + tid*160;
      for (int e = es; e < ee; ++e) {
        int c = (int)ccol[e];
        row[c] = f2h(h2f(row[c]) + 2.f*cw[e]);   // L2 = 2*Lhat
      }
    }
  }
}

// ---------------- layer 1: fused 5 sparse props (din=3), writes Tall[N][18] fp32 ----------------
__global__ __launch_bounds__(512) void k_cheb3(const float* __restrict__ x,
                                               const int* __restrict__ rowptr,
                                               const unsigned char* __restrict__ ccol,
                                               const float* __restrict__ cw,
                                               float* __restrict__ tall) {
  __shared__ float Ta[450], Tb[450];
  __shared__ float cw_s[PJ*DEG];
  __shared__ u16  col_s[PJ*DEG];
  __shared__ int  rp_s[PJ+1];
  int j = blockIdx.x, tid = threadIdx.x;
  int jb = j*PJ, e0 = jb*DEG;
  for (int i = tid; i < PJ*DEG; i += 512) { cw_s[i] = cw[e0+i]; col_s[i] = (u16)ccol[e0+i]; }
  for (int i = tid; i < PJ+1; i += 512) rp_s[i] = rowptr[jb+i] - e0;
  if (tid < 450) Ta[tid] = x[(size_t)jb*3 + tid];
  __syncthreads();
  int r = tid/3, c = tid - r*3;
  float* cur = Ta; float* oth = Tb;
  if (tid < 450) tall[(size_t)(jb+r)*18 + c] = cur[tid];
  for (int t = 1; t < 6; ++t) {
    if (tid < 450) {
      int es = rp_s[r], ee = rp_s[r+1];
      float acc = 0.f;
      for (int e = es; e < ee; ++e) acc += cw_s[e]*cur[(int)col_s[e]*3 + c];
      float v = (t == 1) ? acc : 2.f*acc - oth[tid];
      oth[tid] = v;
      tall[(size_t)(jb+r)*18 + t*3 + c] = v;
    }
    __syncthreads();
    float* tmp = cur; cur = oth; oth = tmp;
  }
}

// out[n,c] = sum_{i<18} Tall[n,i] * W1[i,c]
template<typename OT>
__global__ __launch_bounds__(256) void k_gemm1(const float* __restrict__ tall, const float* __restrict__ W1,
                                               OT* __restrict__ outc) {
  __shared__ float wl[18*256];
  __shared__ float tl[64*18];
  int c = threadIdx.x;
  for (int i = c; i < 18*256; i += 256) wl[i] = W1[i];
  int n0 = blockIdx.x*64;
  __syncthreads();
  for (int i = c; i < 64*18; i += 256) tl[i] = tall[(size_t)n0*18 + i];
  __syncthreads();
  for (int n = 0; n < 64; ++n) {
    float acc = 0.f;
#pragma unroll
    for (int i = 0; i < 18; ++i) acc += tl[n*18 + i] * wl[i*256 + c];
    stv(&outc[(size_t)(n0+n)*HD + c], acc);
  }
}

// ---------------- W prep: WT[cout][k] f16, k = term*256 + cin ----------------
__global__ __launch_bounds__(256) void k_prepW(const float* __restrict__ W, u16* __restrict__ WT) {
  int i = blockIdx.x*256 + threadIdx.x;
  if (i >= 256*1536) return;
  int cout = i / 1536, k = i - cout*1536;
  int term = k >> 8, cin = k & 255;
  WT[i] = f2h(W[(size_t)term*65536 + cin*256 + cout]);
}

// ---------------- fused per-jet Chebyshev layer, all-MFMA, 16 waves (4/SIMD) ----------------
// Block = jet (1024 thr, 16 waves = 2M x 8N). LDS unchanged vs r8 (145.4 KB, 1 block/CU)
// but 4 waves/SIMD double latency hiding. Weight GEMM: wave tile 80x32. Prop: each wave
// owns one half's 16-channel slice (wn>>2 = half, wn&3 = slice). T_{t-1} in registers.
template<typename OT>
__global__ __launch_bounds__(1024, 4) void k_cheb(const u16* __restrict__ X,
                                                  const u16* __restrict__ WTu,
                                                  const u16* __restrict__ Lg,
                                                  const float* __restrict__ bias,
                                                  float* __restrict__ stats,
                                                  OT* __restrict__ OUTp) {
  __shared__ u16 Ls[160*LSTR];
  __shared__ u16 Tn[2][160*TSTR];
  __shared__ u16 Tt[2][64*LSTR];
  int j = blockIdx.x, tid = threadIdx.x;
  int jb = j*PJ;
  int lane = tid & 63, wid = tid >> 6;
  int wm = wid >> 3, wn = wid & 7;          // 2(M) x 8(N)
  int lr = lane & 15, lg = lane >> 4;
  int ph = wn >> 2, cs = wn & 3;            // prop: half + 16-ch slice
  int cown = cs*16 + lr;
  const f16* WT = (const f16*)WTu;

  // stage dense L once
  {
    const u16* src = Lg + (size_t)j*25600;
    for (int i = tid; i < 3200; i += 1024) {
      int row = i/20, seg = i - row*20;
      *(u16x8*)&Ls[row*LSTR + seg*8] = *(const u16x8*)&src[row*160 + seg*8];
    }
  }
  f32x4 acc[5][2];
#pragma unroll
  for (int a = 0; a < 5; ++a)
#pragma unroll
    for (int b = 0; b < 2; ++b) acc[a][b] = (f32x4)0.f;

  for (int qp = 0; qp < 2; ++qp) {
    __syncthreads();   // prior-pair reads done (and L staged at qp=0)
    // stage Tn[0], Tn[1] from X quarters (qp*2, qp*2+1); zero rows 150..159
    for (int i = tid; i < 2560; i += 1024) {
      int h = (i >= 1280) ? 1 : 0;
      int rem = i - h*1280;
      int row = rem >> 3, seg = rem & 7;
      u16x8 v = {0,0,0,0,0,0,0,0};
      if (row < PJ) v = *(const u16x8*)&X[(size_t)(jb+row)*HD + (qp*2+h)*64 + seg*8];
      *(u16x8*)&Tn[h][row*TSTR + seg*8] = v;
    }
    __syncthreads();
    // build Ttr (bank-spread mapping)
    for (int i = tid; i < 2560; i += 1024) {
      int h = (i >= 1280) ? 1 : 0;
      int rem = i - h*1280;
      int c = rem & 63, m = rem >> 6;
      u16x8 v;
#pragma unroll
      for (int u = 0; u < 8; ++u) v[u] = Tn[h][(m*8+u)*TSTR + c];
      *(u16x8*)&Tt[h][c*LSTR + m*8] = v;
    }
    // own-slot T0 registers (this wave's half only)
    u16x4 tcur[5], tprev[5];
#pragma unroll
    for (int mf = 0; mf < 5; ++mf) {
      int r0 = wm*80 + mf*16 + lg*4;
#pragma unroll
      for (int e = 0; e < 4; ++e) tcur[mf][e] = Tn[ph][(r0+e)*TSTR + cown];
      tprev[mf] = tcur[mf];
    }
    __syncthreads();
#pragma unroll 1
    for (int t = 0; t < 6; ++t) {
      // ---- weight GEMM, both halves: acc += T_t @ W_t (wave tile 80x32) ----
#pragma unroll
      for (int h = 0; h < 2; ++h) {
        int kbase = t*256 + (qp*2+h)*64;
#pragma unroll
        for (int ks = 0; ks < 64; ks += 32) {
          f16x8 a[5], bv[2];
#pragma unroll
          for (int nf = 0; nf < 2; ++nf)
            bv[nf] = *(const f16x8*)&WT[(size_t)(wn*32 + nf*16 + lr)*1536 + kbase + ks + lg*8];
#pragma unroll
          for (int mf = 0; mf < 5; ++mf)
            a[mf] = *(const f16x8*)&Tn[h][(wm*80 + mf*16 + lr)*TSTR + ks + lg*8];
#pragma unroll
          for (int nf = 0; nf < 2; ++nf)
#pragma unroll
            for (int mf = 0; mf < 5; ++mf)
              acc[mf][nf] = __builtin_amdgcn_mfma_f32_16x16x32_f16(a[mf], bv[nf], acc[mf][nf], 0, 0, 0);
        }
      }
      if (t < 5) {
        // ---- prop MFMA: pacc = L2 @ T_t for this wave's (half, 16-ch slice) ----
        f32x4 pacc[5];
#pragma unroll
        for (int mf = 0; mf < 5; ++mf) pacc[mf] = (f32x4)0.f;
#pragma unroll
        for (int ks = 0; ks < 5; ++ks) {
          f16x8 b = *(const f16x8*)&Tt[ph][cown*LSTR + ks*32 + lg*8];
#pragma unroll
          for (int mf = 0; mf < 5; ++mf) {
            f16x8 a = *(const f16x8*)&Ls[(wm*80 + mf*16 + lr)*LSTR + ks*32 + lg*8];
            pacc[mf] = __builtin_amdgcn_mfma_f32_16x16x32_f16(a, b, pacc[mf], 0, 0, 0);
          }
        }
        __syncthreads();   // all Tn/Tt reads of term t complete
        // epilogue: T_{t+1} = pacc - T_{t-1} (0.5*pacc at t=0); owner-exclusive slots
#pragma unroll
        for (int mf = 0; mf < 5; ++mf) {
          int r0 = wm*80 + mf*16 + lg*4;
          u16x4 o;
#pragma unroll
          for (int e = 0; e < 4; ++e) {
            float v = (t == 0) ? 0.5f*pacc[mf][e]
                               : pacc[mf][e] - h2f(tprev[mf][e]);
            o[e] = f2h(v);
            Tn[ph][(r0+e)*TSTR + cown] = o[e];
          }
          *(u16x4*)&Tt[ph][cown*LSTR + r0] = o;
          tprev[mf] = tcur[mf];
          tcur[mf] = o;
        }
        __syncthreads();
      }
    }
  }
  // ---- OUT epilogue + fused BN stats ----
#pragma unroll
  for (int nf = 0; nf < 2; ++nf) {
    int col = wn*32 + nf*16 + lr;
    float bc = bias[col];
    float s = 0.f, s2 = 0.f;
#pragma unroll
    for (int mf = 0; mf < 5; ++mf) {
      int row = wm*80 + mf*16 + lg*4;
#pragma unroll
      for (int e = 0; e < 4; ++e) {
        int r = row + e;
        if (r < PJ) {
          float v = acc[mf][nf][e];
          stv(&OUTp[(size_t)(jb+r)*HD + col], v);
          float vb = v + bc;
          s += vb; s2 += vb*vb;
        }
      }
    }
    s  += __shfl_xor(s, 16, 64);  s  += __shfl_xor(s, 32, 64);
    s2 += __shfl_xor(s2, 16, 64); s2 += __shfl_xor(s2, 32, 64);
    if (lg == 0) {
      atomicAdd(&stats[col], s);
      atomicAdd(&stats[HD + col], s2);
    }
  }
}

// ---------------- batchnorm stats (layer 1 only) ----------------

template<typename OT>
__global__ __launch_bounds__(256) void k_bnstats(const OT* __restrict__ Cc, const float* __restrict__ bias,
                                                 float* __restrict__ stats) {
  int c = threadIdx.x;
  float bc = bias[c];
  float s = 0.f, s2 = 0.f;
  int rows_per = (NODES + gridDim.x - 1) / gridDim.x;
  int r0 = blockIdx.x * rows_per;
  int r1 = min(NODES, r0 + rows_per);
  for (int r = r0; r < r1; ++r) {
    float v = ldv(&Cc[(size_t)r*HD + c]) + bc;
    s += v; s2 += v*v;
  }
  atomicAdd(&stats[c], s);
  atomicAdd(&stats[HD + c], s2);
}

template<typename OT>
__global__ __launch_bounds__(256) void k_bnapply(const OT* __restrict__ Cc, const float* __restrict__ bias,
                                                 const float* __restrict__ stats, const float* __restrict__ g,
                                                 const float* __restrict__ be, u16* __restrict__ hout) {
  const float invN = 1.f/(float)NODES;
  int total = NODES*HD;
  for (int i = blockIdx.x*256 + threadIdx.x; i < total; i += gridDim.x*256) {
    int c = i & (HD-1);
    float m = stats[c]*invN;
    float v = stats[HD+c]*invN - m*m;
    float wq = rsqrtf(v + 1e-5f);
    float val = (ldv(&Cc[i]) + bias[c] - m)*wq*g[c] + be[c];
    hout[i] = f2h((val > 0.f) ? val : 0.01f*val);
  }
}

// ---------------- row L2 normalize (layer 4 output) ----------------

template<typename OT>
__global__ __launch_bounds__(256) void k_rownorm(const OT* __restrict__ Cc, const float* __restrict__ bias,
                                                 u16* __restrict__ hout) {
  int wave = threadIdx.x >> 6, lane = threadIdx.x & 63;
  int n = blockIdx.x*4 + wave;
  float v0 = ldv(&Cc[(size_t)n*HD + lane*4 + 0]) + bias[lane*4 + 0];
  float v1 = ldv(&Cc[(size_t)n*HD + lane*4 + 1]) + bias[lane*4 + 1];
  float v2 = ldv(&Cc[(size_t)n*HD + lane*4 + 2]) + bias[lane*4 + 2];
  float v3 = ldv(&Cc[(size_t)n*HD + lane*4 + 3]) + bias[lane*4 + 3];
  float ss = v0*v0 + v1*v1 + v2*v2 + v3*v3;
  for (int off = 32; off > 0; off >>= 1) ss += __shfl_down(ss, off, 64);
  ss = __shfl(ss, 0, 64);
  float inv = 1.f / fmaxf(sqrtf(ss), 1e-12f);
  hout[(size_t)n*HD + lane*4 + 0] = f2h(v0*inv);
  hout[(size_t)n*HD + lane*4 + 1] = f2h(v1*inv);
  hout[(size_t)n*HD + lane*4 + 2] = f2h(v2*inv);
  hout[(size_t)n*HD + lane*4 + 3] = f2h(v3*inv);
}

// ---------------- distance softmax pooling ----------------

__global__ __launch_bounds__(256) void k_pool(const u16* __restrict__ h, const float* __restrict__ x,
                                              const float* __restrict__ centers, const float* __restrict__ log_temp,
                                              float* __restrict__ out) {
  __shared__ float a_s[PJ][NCL];
  __shared__ float colsum[NCL];
  int j = blockIdx.x;
  int tid = threadIdx.x;
  float T = expf(fminf(fmaxf(log_temp[0], -2.f), 3.f));
  if (tid < PJ) {
    int g = j*PJ + tid;
    float eta = x[(size_t)g*3], phi = x[(size_t)g*3 + 1];
    float d[NCL];
    float dmin = 1e30f;
#pragma unroll
    for (int k = 0; k < NCL; ++k) {
      float dx = eta - centers[2*k], dy = phi - centers[2*k+1];
      d[k] = dx*dx + dy*dy;
      dmin = fminf(dmin, d[k]);
    }
    float s = 0.f, ek[NCL];
#pragma unroll
    for (int k = 0; k < NCL; ++k) { ek[k] = expf(-T*(d[k]-dmin)); s += ek[k]; }
    float invs = 1.f/s;
#pragma unroll
    for (int k = 0; k < NCL; ++k) a_s[tid][k] = ek[k]*invs;
  }
  __syncthreads();
  if (tid < NCL) {
    float s = 0.f;
    for (int n = 0; n < PJ; ++n) s += a_s[n][tid];
    colsum[tid] = s;
  }
  __syncthreads();
  int c = tid;
  float acc[NCL] = {};
  for (int n = 0; n < PJ; ++n) {
    float hv = h2f(h[(size_t)(j*PJ + n)*HD + c]);
#pragma unroll
    for (int k = 0; k < NCL; ++k) acc[k] += a_s[n][k]*hv;
  }
#pragma unroll
  for (int k = 0; k < NCL; ++k)
    out[(size_t)j*(NCL*HD) + k*HD + c] = acc[k] / (colsum[k] + 1e-8f);
}

// ---------------- host ----------------

template<typename OT>
static void run_plan(const float* x, const int* srcA, const int* tgtA,
                     const float* W1, const float* b1, const float* W2, const float* b2,
                     const float* W3, const float* b3, const float* W4, const float* b4,
                     const float* g1, const float* be1, const float* g2, const float* be2,
                     const float* g3, const float* be3, const float* centers, const float* log_temp,
                     float* out, char* wp0, hipStream_t stream) {
  char* wp = wp0;
  auto alloc = [&](size_t b) -> void* {
    void* p = (void*)wp;
    wp += (b + 255) & ~(size_t)255;
    return p;
  };
  u16*   X    = (u16*)alloc((size_t)NODES*HD*2);
  u16*   Y    = (u16*)alloc((size_t)NODES*HD*2);
  OT*    OUT  = (OT*)alloc((size_t)NODES*HD*sizeof(OT));
  float* dis  = (float*)alloc((size_t)NODES*4);
  int*   counts = (int*)alloc((size_t)NODES*4);
  int*   cursor = (int*)alloc((size_t)NODES*4);
  int*   rowptr = (int*)alloc((size_t)(NODES+1)*4);
  unsigned char* ccol = (unsigned char*)alloc((size_t)NEDGE);
  float* cw     = (float*)alloc((size_t)NEDGE*4);
  float* stats  = (float*)alloc((size_t)2*HD*4);
  // aliases into Y: layer-1 Tall (11 MB) first, then Lg (52.4 MB) + Wcat (0.8 MB)
  float* Tall = (float*)Y;
  u16*   Lg   = Y;
  u16*   Wcat = Y + (size_t)NJETS*160*160;

  // graph preprocessing
  hipMemsetAsync(counts, 0, (size_t)NODES*4, stream);
  k_dis<<<(NODES+255)/256, 256, 0, stream>>>(tgtA, dis);
  k_counts<<<(NEDGE+255)/256, 256, 0, stream>>>(tgtA, counts);
  k_scan<<<(NJETS+255)/256, 256, 0, stream>>>(counts, rowptr, cursor);
  k_fill<<<(NEDGE+255)/256, 256, 0, stream>>>(srcA, tgtA, dis, cursor, ccol, cw);

  // ---- layer 1 (din=3): fused props + small GEMM + BN ----
  k_cheb3<<<NJETS, 512, 0, stream>>>(x, rowptr, ccol, cw, Tall);
  k_gemm1<OT><<<NODES/64, 256, 0, stream>>>(Tall, W1, OUT);
  hipMemsetAsync(stats, 0, (size_t)2*HD*4, stream);
  k_bnstats<OT><<<1024, 256, 0, stream>>>(OUT, b1, stats);
  k_bnapply<OT><<<4096, 256, 0, stream>>>(OUT, b1, stats, g1, be1, X);

  // ---- dense Laplacian (after layer 1 frees the Y scratch) ----
  k_prepL<<<NJETS, 256, 0, stream>>>(rowptr, ccol, cw, Lg);

  // ---- layers 2..4: fused all-MFMA Cheb (stats fused into epilogue) ----
  const float* Ws[3]  = {W2, W3, W4};
  const float* bs[3]  = {b2, b3, b4};
  const float* gs[2]  = {g2, g3};
  const float* bes[2] = {be2, be3};
  for (int L = 0; L < 3; ++L) {
    k_prepW<<<1536, 256, 0, stream>>>(Ws[L], Wcat);
    hipMemsetAsync(stats, 0, (size_t)2*HD*4, stream);
    k_cheb<OT><<<NJETS, 1024, 0, stream>>>(X, Wcat, Lg, bs[L], stats, OUT);
    if (L < 2) {
      k_bnapply<OT><<<4096, 256, 0, stream>>>(OUT, bs[L], stats, gs[L], bes[L], X);
    } else {
      k_rownorm<OT><<<NODES/4, 256, 0, stream>>>(OUT, bs[L], X);
    }
  }

  // ---- pooling ----
  k_pool<<<NJETS, 256, 0, stream>>>(X, x, centers, log_temp, out);
}

extern "C" void kernel_launch(void* const* d_in, const int* in_sizes, int n_in,
                              void* d_out, int out_size, void* d_ws, size_t ws_size,
                              hipStream_t stream) {
  (void)in_sizes; (void)n_in; (void)out_size;
  const float* x   = (const float*)d_in[0];
  const int*   ei  = (const int*)d_in[1];
  const int*   srcA = ei;
  const int*   tgtA = ei + NEDGE;
  const float* W1  = (const float*)d_in[3];
  const float* b1  = (const float*)d_in[4];
  const float* W2  = (const float*)d_in[5];
  const float* b2  = (const float*)d_in[6];
  const float* W3  = (const float*)d_in[7];
  const float* b3  = (const float*)d_in[8];
  const float* W4  = (const float*)d_in[9];
  const float* b4  = (const float*)d_in[10];
  const float* g1  = (const float*)d_in[11];
  const float* be1 = (const float*)d_in[12];
  const float* g2  = (const float*)d_in[13];
  const float* be2 = (const float*)d_in[14];
  const float* g3  = (const float*)d_in[15];
  const float* be3 = (const float*)d_in[16];
  const float* centers  = (const float*)d_in[17];
  const float* log_temp = (const float*)d_in[18];
  float* out = (float*)d_out;

  auto rb = [](size_t b) { return (b + 255) & ~(size_t)255; };
  auto plan_bytes = [&](size_t out_esz) {
    return 2*rb((size_t)NODES*HD*2) + rb((size_t)NODES*HD*out_esz)
         + 3*rb((size_t)NODES*4) + rb((size_t)(NODES+1)*4)
         + rb((size_t)NEDGE) + rb((size_t)NEDGE*4) + rb((size_t)2*HD*4);
  };
  size_t needA = plan_bytes(4);
  size_t needB = plan_bytes(2);
  fprintf(stderr, "[kernel_launch] ws_size=%zu needA=%zu needB=%zu\n", ws_size, needA, needB);

  if (d_ws == nullptr || ws_size < needB) {
    float code = 1.0e6f + (float)(ws_size >> 20);
    k_diag<<<1, 1, 0, stream>>>(out, code);
    return;
  }

  if (ws_size >= needA)
    run_plan<float>(x, srcA, tgtA, W1, b1, W2, b2, W3, b3, W4, b4,
                    g1, be1, g2, be2, g3, be3, centers, log_temp,
                    out, (char*)d_ws, stream);
  else
    run_plan<u16>(x, srcA, tgtA, W1, b1, W2, b2, W3, b3, W4, b4,
                  g1, be1, g2, be2, g3, be3, centers, log_temp,
                  out, (char*)d_ws, stream);
}

// Round 10
// 1387.790 us; speedup vs baseline: 1.6839x; 1.1124x over previous
//
#include <hip/hip_runtime.h>
#include <cstdio>

#define NODES 153600
#define PJ 150
#define NJETS 1024
#define DEG 16
#define NEDGE (NODES*DEG)
#define HD 256
#define NCL 10

#define LSTR 168   // padded stride (u16) for Ls/Tt rows: 21 quads ≡ 5 mod 8 -> spread
#define TSTR 72    // padded stride (u16) for Tn rows: 144B, 16B-aligned, 9 quads ≡ 1 mod 8 -> spread

typedef unsigned short u16;  // fp16 bit pattern
typedef _Float16 f16;
typedef f16 f16x8 __attribute__((ext_vector_type(8)));
typedef u16 u16x8 __attribute__((ext_vector_type(8)));
typedef u16 u16x4 __attribute__((ext_vector_type(4)));
typedef float f32x4 __attribute__((ext_vector_type(4)));

__device__ inline float h2f(u16 u) { union { u16 s; f16 h; } v; v.s = u; return (float)v.h; }
__device__ inline u16 f2h(float f) { union { u16 s; f16 h; } v; v.h = (f16)f; return v.s; }

// ---------------- diagnostic ----------------
__global__ void k_diag(float* out, float code) {
  if (blockIdx.x == 0 && threadIdx.x == 0) out[0] = code;
}

// ---------------- graph preprocessing ----------------

__global__ __launch_bounds__(256) void k_dis(const int* __restrict__ tgt, float* __restrict__ dis) {
  int n = blockIdx.x*256 + threadIdx.x;
  if (n >= NODES) return;
  int cnt = 0;
#pragma unroll
  for (int j = 0; j < DEG; ++j) cnt += (tgt[n*DEG + j] != n) ? 1 : 0;
  dis[n] = (cnt > 0) ? rsqrtf((float)cnt) : 0.f;
}

__global__ __launch_bounds__(256) void k_counts(const int* __restrict__ tgt, int* __restrict__ counts) {
  int e = blockIdx.x*256 + threadIdx.x;
  if (e >= NEDGE) return;
  atomicAdd(&counts[tgt[e]], 1);
}

__global__ __launch_bounds__(256) void k_scan(const int* __restrict__ counts, int* __restrict__ rowptr, int* __restrict__ cursor) {
  int j = blockIdx.x*256 + threadIdx.x;
  if (j >= NJETS) return;
  int run = j*PJ*DEG;
  for (int l = 0; l < PJ; ++l) {
    int idx = j*PJ + l;
    int cnt = counts[idx];
    rowptr[idx] = run;
    cursor[idx] = run;
    run += cnt;
  }
  if (j == 0) rowptr[NODES] = NEDGE;
}

__global__ __launch_bounds__(256) void k_fill(const int* __restrict__ src_, const int* __restrict__ tgt_,
                                              const float* __restrict__ dis, int* __restrict__ cursor,
                                              unsigned char* __restrict__ ccol, float* __restrict__ cw) {
  int e = blockIdx.x*256 + threadIdx.x;
  if (e >= NEDGE) return;
  int s = src_[e], t = tgt_[e];
  int pos = atomicAdd(&cursor[t], 1);
  ccol[pos] = (unsigned char)(s % PJ);
  cw[pos] = (s != t) ? -(dis[s]*dis[t]) : 0.f;
}

// ---------------- dense per-jet 2*Laplacian: Lg[jet][160][160] f16 ----------------
__global__ __launch_bounds__(256) void k_prepL(const int* __restrict__ rowptr,
                                               const unsigned char* __restrict__ ccol,
                                               const float* __restrict__ cw,
                                               u16* __restrict__ Lg) {
  int j = blockIdx.x, tid = threadIdx.x;
  u16* L = Lg + (size_t)j*160*160;
  if (tid < 160) {
    u16x8 z = {0,0,0,0,0,0,0,0};
    for (int seg = 0; seg < 20; ++seg) *(u16x8*)&L[tid*160 + seg*8] = z;
    if (tid < PJ) {
      int es = rowptr[j*PJ + tid], ee = rowptr[j*PJ + tid + 1];
      u16* row = L + tid*160;
      for (int e = es; e < ee; ++e) {
        int c = (int)ccol[e];
        row[c] = f2h(h2f(row[c]) + 2.f*cw[e]);   // L2 = 2*Lhat
      }
    }
  }
}

// ---------------- layer 1: fused 5 sparse props (din=3), writes Tall[N][18] fp32 ----------------
__global__ __launch_bounds__(512) void k_cheb3(const float* __restrict__ x,
                                               const int* __restrict__ rowptr,
                                               const unsigned char* __restrict__ ccol,
                                               const float* __restrict__ cw,
                                               float* __restrict__ tall) {
  __shared__ float Ta[450], Tb[450];
  __shared__ float cw_s[PJ*DEG];
  __shared__ u16  col_s[PJ*DEG];
  __shared__ int  rp_s[PJ+1];
  int j = blockIdx.x, tid = threadIdx.x;
  int jb = j*PJ, e0 = jb*DEG;
  for (int i = tid; i < PJ*DEG; i += 512) { cw_s[i] = cw[e0+i]; col_s[i] = (u16)ccol[e0+i]; }
  for (int i = tid; i < PJ+1; i += 512) rp_s[i] = rowptr[jb+i] - e0;
  if (tid < 450) Ta[tid] = x[(size_t)jb*3 + tid];
  __syncthreads();
  int r = tid/3, c = tid - r*3;
  float* cur = Ta; float* oth = Tb;
  if (tid < 450) tall[(size_t)(jb+r)*18 + c] = cur[tid];
  for (int t = 1; t < 6; ++t) {
    if (tid < 450) {
      int es = rp_s[r], ee = rp_s[r+1];
      float acc = 0.f;
      for (int e = es; e < ee; ++e) acc += cw_s[e]*cur[(int)col_s[e]*3 + c];
      float v = (t == 1) ? acc : 2.f*acc - oth[tid];
      oth[tid] = v;
      tall[(size_t)(jb+r)*18 + t*3 + c] = v;
    }
    __syncthreads();
    float* tmp = cur; cur = oth; oth = tmp;
  }
}

// out[n,c] = sum_{i<18} Tall[n,i] * W1[i,c]; fused BN stats (with bias b1)
__global__ __launch_bounds__(256) void k_gemm1(const float* __restrict__ tall, const float* __restrict__ W1,
                                               const float* __restrict__ b1, float* __restrict__ stats,
                                               u16* __restrict__ outc) {
  __shared__ float wl[18*256];
  __shared__ float tl[64*18];
  int c = threadIdx.x;
  for (int i = c; i < 18*256; i += 256) wl[i] = W1[i];
  int n0 = blockIdx.x*64;
  __syncthreads();
  for (int i = c; i < 64*18; i += 256) tl[i] = tall[(size_t)n0*18 + i];
  __syncthreads();
  float bc = b1[c];
  float s = 0.f, s2 = 0.f;
  for (int n = 0; n < 64; ++n) {
    float acc = 0.f;
#pragma unroll
    for (int i = 0; i < 18; ++i) acc += tl[n*18 + i] * wl[i*256 + c];
    outc[(size_t)(n0+n)*HD + c] = f2h(acc);
    float vb = acc + bc;
    s += vb; s2 += vb*vb;
  }
  atomicAdd(&stats[c], s);
  atomicAdd(&stats[HD + c], s2);
}

// ---------------- W prep: WT[cout][k] f16, k = term*256 + cin ----------------
__global__ __launch_bounds__(256) void k_prepW(const float* __restrict__ W, u16* __restrict__ WT) {
  int i = blockIdx.x*256 + threadIdx.x;
  if (i >= 256*1536) return;
  int cout = i / 1536, k = i - cout*1536;
  int term = k >> 8, cin = k & 255;
  WT[i] = f2h(W[(size_t)term*65536 + cin*256 + cout]);
}

// ---------------- fused per-jet Chebyshev layer ----------------
// Input = raw OUT of previous layer; BN(affine from statsPrev/gP/beP/bP)+LeakyReLU applied
// during T0 staging. Epilogue: OMODE 0 -> BN stats (bias bCur) for the NEXT layer;
// OMODE 1 -> per-row sum((v+bCur)^2) into rn[] for the rownorm+pool.
template<int OMODE>
__global__ __launch_bounds__(1024, 4) void k_cheb(const u16* __restrict__ IN,
                                                  const u16* __restrict__ WTu,
                                                  const u16* __restrict__ Lg,
                                                  const float* __restrict__ statsPrev,
                                                  const float* __restrict__ gP,
                                                  const float* __restrict__ beP,
                                                  const float* __restrict__ bP,
                                                  const float* __restrict__ bCur,
                                                  float* __restrict__ statsCur,
                                                  float* __restrict__ rn,
                                                  u16* __restrict__ OUTp) {
  __shared__ u16 Ls[160*LSTR];
  __shared__ u16 Tn[2][160*TSTR];
  __shared__ u16 Tt[2][64*LSTR];
  __shared__ float bnA[HD], bnB[HD];
  int j = blockIdx.x, tid = threadIdx.x;
  int jb = j*PJ;
  int lane = tid & 63, wid = tid >> 6;
  int wm = wid >> 3, wn = wid & 7;          // 2(M) x 8(N)
  int lr = lane & 15, lg = lane >> 4;
  int ph = wn >> 2, cs = wn & 3;            // prop: half + 16-ch slice
  int cown = cs*16 + lr;
  const f16* WT = (const f16*)WTu;

  // BN tables: staged value = lrelu(IN*A + B)
  if (tid < HD) {
    const float invN = 1.f/(float)NODES;
    float m = statsPrev[tid]*invN;
    float var = statsPrev[HD+tid]*invN - m*m;
    float A = rsqrtf(var + 1e-5f) * gP[tid];
    bnA[tid] = A;
    bnB[tid] = (bP[tid] - m)*A + beP[tid];
  }
  // stage dense L once
  {
    const u16* src = Lg + (size_t)j*25600;
    for (int i = tid; i < 3200; i += 1024) {
      int row = i/20, seg = i - row*20;
      *(u16x8*)&Ls[row*LSTR + seg*8] = *(const u16x8*)&src[row*160 + seg*8];
    }
  }
  f32x4 acc[5][2];
#pragma unroll
  for (int a = 0; a < 5; ++a)
#pragma unroll
    for (int b = 0; b < 2; ++b) acc[a][b] = (f32x4)0.f;

  for (int qp = 0; qp < 2; ++qp) {
    __syncthreads();   // prior-pair reads done; bn/L staged at qp=0
    // stage T0 = lrelu(BN(IN)) for quarters (qp*2, qp*2+1); zero rows 150..159
    for (int i = tid; i < 2560; i += 1024) {
      int h = (i >= 1280) ? 1 : 0;
      int rem = i - h*1280;
      int row = rem >> 3, seg = rem & 7;
      u16x8 o = {0,0,0,0,0,0,0,0};
      if (row < PJ) {
        int c0 = (qp*2+h)*64 + seg*8;
        u16x8 v = *(const u16x8*)&IN[(size_t)(jb+row)*HD + c0];
#pragma unroll
        for (int u = 0; u < 8; ++u) {
          float f = h2f(v[u])*bnA[c0+u] + bnB[c0+u];
          o[u] = f2h((f > 0.f) ? f : 0.01f*f);
        }
      }
      *(u16x8*)&Tn[h][row*TSTR + seg*8] = o;
    }
    __syncthreads();
    // build Ttr (bank-spread mapping)
    for (int i = tid; i < 2560; i += 1024) {
      int h = (i >= 1280) ? 1 : 0;
      int rem = i - h*1280;
      int c = rem & 63, m = rem >> 6;
      u16x8 v;
#pragma unroll
      for (int u = 0; u < 8; ++u) v[u] = Tn[h][(m*8+u)*TSTR + c];
      *(u16x8*)&Tt[h][c*LSTR + m*8] = v;
    }
    // own-slot T0 registers (this wave's half only)
    u16x4 tcur[5], tprev[5];
#pragma unroll
    for (int mf = 0; mf < 5; ++mf) {
      int r0 = wm*80 + mf*16 + lg*4;
#pragma unroll
      for (int e = 0; e < 4; ++e) tcur[mf][e] = Tn[ph][(r0+e)*TSTR + cown];
      tprev[mf] = tcur[mf];
    }
    __syncthreads();
#pragma unroll 1
    for (int t = 0; t < 6; ++t) {
      // ---- weight GEMM, both halves: acc += T_t @ W_t (wave tile 80x32) ----
#pragma unroll
      for (int h = 0; h < 2; ++h) {
        int kbase = t*256 + (qp*2+h)*64;
#pragma unroll
        for (int ks = 0; ks < 64; ks += 32) {
          f16x8 a[5], bv[2];
#pragma unroll
          for (int nf = 0; nf < 2; ++nf)
            bv[nf] = *(const f16x8*)&WT[(size_t)(wn*32 + nf*16 + lr)*1536 + kbase + ks + lg*8];
#pragma unroll
          for (int mf = 0; mf < 5; ++mf)
            a[mf] = *(const f16x8*)&Tn[h][(wm*80 + mf*16 + lr)*TSTR + ks + lg*8];
#pragma unroll
          for (int nf = 0; nf < 2; ++nf)
#pragma unroll
            for (int mf = 0; mf < 5; ++mf)
              acc[mf][nf] = __builtin_amdgcn_mfma_f32_16x16x32_f16(a[mf], bv[nf], acc[mf][nf], 0, 0, 0);
        }
      }
      if (t < 5) {
        // ---- prop MFMA: pacc = L2 @ T_t for this wave's (half, 16-ch slice) ----
        f32x4 pacc[5];
#pragma unroll
        for (int mf = 0; mf < 5; ++mf) pacc[mf] = (f32x4)0.f;
#pragma unroll
        for (int ks = 0; ks < 5; ++ks) {
          f16x8 b = *(const f16x8*)&Tt[ph][cown*LSTR + ks*32 + lg*8];
#pragma unroll
          for (int mf = 0; mf < 5; ++mf) {
            f16x8 a = *(const f16x8*)&Ls[(wm*80 + mf*16 + lr)*LSTR + ks*32 + lg*8];
            pacc[mf] = __builtin_amdgcn_mfma_f32_16x16x32_f16(a, b, pacc[mf], 0, 0, 0);
          }
        }
        __syncthreads();   // all Tn/Tt reads of term t complete
        // epilogue: T_{t+1} = pacc - T_{t-1} (0.5*pacc at t=0); owner-exclusive slots
#pragma unroll
        for (int mf = 0; mf < 5; ++mf) {
          int r0 = wm*80 + mf*16 + lg*4;
          u16x4 o;
#pragma unroll
          for (int e = 0; e < 4; ++e) {
            float v = (t == 0) ? 0.5f*pacc[mf][e]
                               : pacc[mf][e] - h2f(tprev[mf][e]);
            o[e] = f2h(v);
            Tn[ph][(r0+e)*TSTR + cown] = o[e];
          }
          *(u16x4*)&Tt[ph][cown*LSTR + r0] = o;
          tprev[mf] = tcur[mf];
          tcur[mf] = o;
        }
        __syncthreads();
      }
    }
  }
  // ---- OUT epilogue + fused stats / rowsumsq ----
  if (OMODE == 0) {
#pragma unroll
    for (int nf = 0; nf < 2; ++nf) {
      int col = wn*32 + nf*16 + lr;
      float bc = bCur[col];
      float s = 0.f, s2 = 0.f;
#pragma unroll
      for (int mf = 0; mf < 5; ++mf) {
        int row = wm*80 + mf*16 + lg*4;
#pragma unroll
        for (int e = 0; e < 4; ++e) {
          int r = row + e;
          if (r < PJ) {
            float v = acc[mf][nf][e];
            OUTp[(size_t)(jb+r)*HD + col] = f2h(v);
            float vb = v + bc;
            s += vb; s2 += vb*vb;
          }
        }
      }
      s  += __shfl_xor(s, 16, 64);  s  += __shfl_xor(s, 32, 64);
      s2 += __shfl_xor(s2, 16, 64); s2 += __shfl_xor(s2, 32, 64);
      if (lg == 0) {
        atomicAdd(&statsCur[col], s);
        atomicAdd(&statsCur[HD + col], s2);
      }
    }
  } else {
    float bc[2];
#pragma unroll
    for (int nf = 0; nf < 2; ++nf) bc[nf] = bCur[wn*32 + nf*16 + lr];
#pragma unroll
    for (int mf = 0; mf < 5; ++mf) {
      int row = wm*80 + mf*16 + lg*4;
#pragma unroll
      for (int e = 0; e < 4; ++e) {
        int r = row + e;
        float srow = 0.f;
        if (r < PJ) {
#pragma unroll
          for (int nf = 0; nf < 2; ++nf) {
            int col = wn*32 + nf*16 + lr;
            float v = acc[mf][nf][e];
            OUTp[(size_t)(jb+r)*HD + col] = f2h(v);
            float vb = v + bc[nf];
            srow += vb*vb;
          }
        }
        srow += __shfl_xor(srow, 1, 64);
        srow += __shfl_xor(srow, 2, 64);
        srow += __shfl_xor(srow, 4, 64);
        srow += __shfl_xor(srow, 8, 64);
        if (lr == 0 && r < PJ) atomicAdd(&rn[jb + r], srow);
      }
    }
  }
}

// ---------------- distance softmax pooling, fused row-normalize ----------------

__global__ __launch_bounds__(256) void k_pool(const u16* __restrict__ h, const float* __restrict__ rn,
                                              const float* __restrict__ bias, const float* __restrict__ x,
                                              const float* __restrict__ centers, const float* __restrict__ log_temp,
                                              float* __restrict__ out) {
  __shared__ float a_s[PJ][NCL];
  __shared__ float colsum[NCL];
  __shared__ float inv_s[PJ];
  int j = blockIdx.x;
  int tid = threadIdx.x;
  float T = expf(fminf(fmaxf(log_temp[0], -2.f), 3.f));
  if (tid < PJ) {
    int g = j*PJ + tid;
    inv_s[tid] = 1.f / fmaxf(sqrtf(rn[g]), 1e-12f);
    float eta = x[(size_t)g*3], phi = x[(size_t)g*3 + 1];
    float d[NCL];
    float dmin = 1e30f;
#pragma unroll
    for (int k = 0; k < NCL; ++k) {
      float dx = eta - centers[2*k], dy = phi - centers[2*k+1];
      d[k] = dx*dx + dy*dy;
      dmin = fminf(dmin, d[k]);
    }
    float s = 0.f, ek[NCL];
#pragma unroll
    for (int k = 0; k < NCL; ++k) { ek[k] = expf(-T*(d[k]-dmin)); s += ek[k]; }
    float invs = 1.f/s;
#pragma unroll
    for (int k = 0; k < NCL; ++k) a_s[tid][k] = ek[k]*invs;
  }
  __syncthreads();
  if (tid < NCL) {
    float s = 0.f;
    for (int n = 0; n < PJ; ++n) s += a_s[n][tid];
    colsum[tid] = s;
  }
  __syncthreads();
  int c = tid;
  float bc = bias[c];
  float acc[NCL] = {};
  for (int n = 0; n < PJ; ++n) {
    float hv = (h2f(h[(size_t)(j*PJ + n)*HD + c]) + bc) * inv_s[n];
#pragma unroll
    for (int k = 0; k < NCL; ++k) acc[k] += a_s[n][k]*hv;
  }
#pragma unroll
  for (int k = 0; k < NCL; ++k)
    out[(size_t)j*(NCL*HD) + k*HD + c] = acc[k] / (colsum[k] + 1e-8f);
}

// ---------------- host ----------------

extern "C" void kernel_launch(void* const* d_in, const int* in_sizes, int n_in,
                              void* d_out, int out_size, void* d_ws, size_t ws_size,
                              hipStream_t stream) {
  (void)in_sizes; (void)n_in; (void)out_size;
  const float* x   = (const float*)d_in[0];
  const int*   ei  = (const int*)d_in[1];
  const int*   srcA = ei;
  const int*   tgtA = ei + NEDGE;
  const float* W1  = (const float*)d_in[3];
  const float* b1  = (const float*)d_in[4];
  const float* W2  = (const float*)d_in[5];
  const float* b2  = (const float*)d_in[6];
  const float* W3  = (const float*)d_in[7];
  const float* b3  = (const float*)d_in[8];
  const float* W4  = (const float*)d_in[9];
  const float* b4  = (const float*)d_in[10];
  const float* g1  = (const float*)d_in[11];
  const float* be1 = (const float*)d_in[12];
  const float* g2  = (const float*)d_in[13];
  const float* be2 = (const float*)d_in[14];
  const float* g3  = (const float*)d_in[15];
  const float* be3 = (const float*)d_in[16];
  const float* centers  = (const float*)d_in[17];
  const float* log_temp = (const float*)d_in[18];
  float* out = (float*)d_out;

  auto rb = [](size_t b) { return (b + 255) & ~(size_t)255; };
  size_t need = 3*rb((size_t)NODES*HD*2)            // OUTA, OUTB, Y
              + 3*rb((size_t)NODES*4)               // dis, counts, cursor
              + rb((size_t)(NODES+1)*4)             // rowptr
              + rb((size_t)NEDGE)                   // ccol
              + rb((size_t)NEDGE*4)                 // cw
              + rb((size_t)3*2*HD*4)                // stats x3
              + rb((size_t)NODES*4);                // rn
  fprintf(stderr, "[kernel_launch] ws_size=%zu need=%zu\n", ws_size, need);
  if (d_ws == nullptr || ws_size < need) {
    float code = 1.0e6f + (float)(ws_size >> 20);
    k_diag<<<1, 1, 0, stream>>>(out, code);
    return;
  }

  char* wp = (char*)d_ws;
  auto alloc = [&](size_t b) -> void* {
    void* p = (void*)wp;
    wp += (b + 255) & ~(size_t)255;
    return p;
  };
  u16*   OUTA = (u16*)alloc((size_t)NODES*HD*2);
  u16*   OUTB = (u16*)alloc((size_t)NODES*HD*2);
  u16*   Y    = (u16*)alloc((size_t)NODES*HD*2);
  float* dis  = (float*)alloc((size_t)NODES*4);
  int*   counts = (int*)alloc((size_t)NODES*4);
  int*   cursor = (int*)alloc((size_t)NODES*4);
  int*   rowptr = (int*)alloc((size_t)(NODES+1)*4);
  unsigned char* ccol = (unsigned char*)alloc((size_t)NEDGE);
  float* cw     = (float*)alloc((size_t)NEDGE*4);
  float* stats  = (float*)alloc((size_t)3*2*HD*4);   // [3][512]
  float* rn     = (float*)alloc((size_t)NODES*4);
  // aliases into Y: layer-1 Tall (11 MB) first, then Lg (52.4 MB) + Wcat (0.8 MB)
  float* Tall = (float*)Y;
  u16*   Lg   = Y;
  u16*   Wcat = Y + (size_t)NJETS*160*160;
  float* s0 = stats, *s1 = stats + 512, *s2 = stats + 1024;

  // graph preprocessing
  hipMemsetAsync(counts, 0, (size_t)NODES*4, stream);
  k_dis<<<(NODES+255)/256, 256, 0, stream>>>(tgtA, dis);
  k_counts<<<(NEDGE+255)/256, 256, 0, stream>>>(tgtA, counts);
  k_scan<<<(NJETS+255)/256, 256, 0, stream>>>(counts, rowptr, cursor);
  k_fill<<<(NEDGE+255)/256, 256, 0, stream>>>(srcA, tgtA, dis, cursor, ccol, cw);

  // ---- layer 1 (din=3): fused props + small GEMM (+stats) ----
  k_cheb3<<<NJETS, 512, 0, stream>>>(x, rowptr, ccol, cw, Tall);
  hipMemsetAsync(s0, 0, (size_t)2*HD*4, stream);
  k_gemm1<<<NODES/64, 256, 0, stream>>>(Tall, W1, b1, s0, OUTA);

  // ---- dense Laplacian (after layer 1 frees the Y scratch) ----
  k_prepL<<<NJETS, 256, 0, stream>>>(rowptr, ccol, cw, Lg);

  // ---- layers 2..4: fused all-MFMA Cheb, BN-on-stage ----
  // layer 2: IN=OUTA (stats s0, g1/be1/b1), bias b2 -> stats s1, OUTB
  k_prepW<<<1536, 256, 0, stream>>>(W2, Wcat);
  hipMemsetAsync(s1, 0, (size_t)2*HD*4, stream);
  k_cheb<0><<<NJETS, 1024, 0, stream>>>(OUTA, Wcat, Lg, s0, g1, be1, b1, b2, s1, rn, OUTB);
  // layer 3: IN=OUTB (stats s1, g2/be2/b2), bias b3 -> stats s2, OUTA
  k_prepW<<<1536, 256, 0, stream>>>(W3, Wcat);
  hipMemsetAsync(s2, 0, (size_t)2*HD*4, stream);
  k_cheb<0><<<NJETS, 1024, 0, stream>>>(OUTB, Wcat, Lg, s1, g2, be2, b2, b3, s2, rn, OUTA);
  // layer 4: IN=OUTA (stats s2, g3/be3/b3), bias b4 -> rowsumsq rn, OUTB
  k_prepW<<<1536, 256, 0, stream>>>(W4, Wcat);
  hipMemsetAsync(rn, 0, (size_t)NODES*4, stream);
  k_cheb<1><<<NJETS, 1024, 0, stream>>>(OUTA, Wcat, Lg, s2, g3, be3, b3, b4, s2, rn, OUTB);

  // ---- pooling (fused rownorm) ----
  k_pool<<<NJETS, 256, 0, stream>>>(OUTB, rn, b4, x, centers, log_temp, out);
}